// Round 4
// baseline (250.135 us; speedup 1.0000x reference)
//
#include <hip/hip_runtime.h>
#include <hip/hip_bf16.h>
#include <math.h>

// ---------------------------------------------------------------------------
// VAE ELBO (chromatin VAE). Sizes fixed by the reference.
//
//  * NB_ENC == NB_DEC == 16, identical binning => ONE nibble histogram serves
//    both the encoder input (log1p counts) and the mixture likelihood.
//  * r3-r5: global per-record atomics too slow => two-phase LDS counting sort.
//  * r7: same-address atomics serialize ~16ns => per-block partial stores.
//  * r8: roles fused as block-ranges.
//  * r12: hipLaunchCooperativeKernel DOES NOT RUN under this harness.
//  * r13: part = register-staged single pass; mid = hist+enc / frag only.
//  * r14: __threadfence = L2 wb/inv on 8 non-coherent XCD L2s => +138us. BAN.
//  * r15: fence-free tail: f64 atomics into dacc[64]; returning-atomic
//    data-dep orders done-counter. mixpois 179->52.6.
//  * r16: swapped-operand MFMA => lane-local softmax (mixpois off top-5);
//    Poisson fused into mixture blocks, grid (1000,4).
//  * r17 (this round): mid was the leader (42us) because each cut bucket was
//    read 4x with 3/4 of entries discarded (quarter-split only existed for
//    LDS). FIX: part now partitions cuts into 1024 quarter-buckets directly
//    (key=(c>>6)<<6|bin>>8; e carries bk[9:8] in spare bits so bkof stays
//    u8; excl eliminated: cur-cnt; 2-level wave scan). mid cut blocks read
//    only their own ~3.9K entries, hist = 8KB, reduction scratch overlays
//    dead w1s => 24KB LDS.
// ---------------------------------------------------------------------------

#define G_      1000
#define C_      1024
#define L_      50
#define K_      16
#define NHID_   16
#define CUT_SCALE   12.5f          // N_TOTAL_CUTS / N_CUTS
#define CELL_SCALE  9.765625f      // N_TOTAL_CELLS / N_CELLS

#define CHUNK_     6144
#define RCAP_CUTQ  4608            // quarter-bucket capacity (mean 3968, +10σ)
#define RCAP_FRAG  9216            // frag bucket capacity (mean 8000)

// ws layout (bytes); [0, ZERO_BYTES) memset per call.
#define GCNTC_OFF  0ull            // u32[1024]
#define GCNTF_OFF  4096ull         // u32[256]
#define DONE_OFF   5120ull         // u32: 64 slots @ stride 16, lvl2 @ [1024]
#define DACC_OFF   9728ull         // f64[64] global ELBO accumulator slots
#define HT_OFF     10240ull        // f32 [16][1024] (atomic-accumulated by mid)
#define ZERO_BYTES 75776ull
#define LATBF_OFF  75776ull        // bf16 [1024][64]
#define LWT_OFF    206848ull       // bf16 [1000][16][64]
#define ENTC_OFF   2254848ull      // u16 [1024][4608]
#define ENTF_OFF   11692032ull     // u16 [256][9216]
#define MERGED_OFF 16410624ull     // u32 [16000][128] nibble hist
#define FRAGU8_OFF 24602624ull     // u8  [1000][1024]
#define LATT_OFF   25626624ull     // f32 [50][1024]
#define WS_NEED    25831424ull

typedef __attribute__((ext_vector_type(8))) short short8;
typedef __attribute__((ext_vector_type(4))) float f32x4;

__device__ __constant__ float LGT[32] = {   // log(n!)
    0.0f, 0.0f, 0.6931471805599453f, 1.791759469228055f, 3.1780538303479458f,
    4.787491742782046f, 6.579251212010101f, 8.525161361065415f,
    10.60460290274525f, 12.801827480081469f, 15.104412573075516f,
    17.502307845873887f, 19.987214495661885f, 22.552163853123425f,
    25.19122118273868f, 27.89927138384089f, 30.671860106080672f,
    33.50507345013689f, 36.39544520803305f, 39.339884187199495f,
    42.335616460753485f, 45.38013889847691f, 48.47118135183523f,
    51.60667556776438f, 54.78472939811232f, 58.00360522298052f,
    61.261701761002f, 64.55753862700633f, 67.88974313718154f,
    71.25703896716801f, 74.65823634883016f, 78.0922235533153f };

// f64 atomic add at the device coherent point (returns old value; the return
// is used to fabricate ordering dependencies — NO fences anywhere).
__device__ __forceinline__ double atomAddF64(double* p, double v) {
    return __hip_atomic_fetch_add(p, v, __ATOMIC_RELAXED,
                                  __HIP_MEMORY_SCOPE_AGENT);
}

__device__ __forceinline__ float block_sum_256(float v) {
    __shared__ float sm[256];
    int t = threadIdx.x;
    __syncthreads();
    sm[t] = v;
    __syncthreads();
#pragma unroll
    for (int s = 128; s > 0; s >>= 1) {
        if (t < s) sm[t] += sm[t + s];
        __syncthreads();
    }
    return sm[0];
}

// --- 1. part: [0,nblk_part) radix partition (1024 cut / 256 frag buckets) |
//        [nblk_part, +256) lwprep | [+256, +512) wkl ------------------------
__global__ __launch_bounds__(256)
void part_kernel(const int* __restrict__ cut_ix,
                 const float* __restrict__ coord,
                 const int* __restrict__ frag_ix,
                 unsigned int* __restrict__ gcnt_c,   // [1024]
                 unsigned int* __restrict__ gcnt_f,   // [256]
                 unsigned short* __restrict__ entc,   // [1024][4608]
                 unsigned short* __restrict__ entf,   // [256][9216]
                 const float* __restrict__ lw,        // [1000][50][16]
                 const float* __restrict__ rw,        // [1000][50]
                 __hip_bfloat16* __restrict__ lwT,    // [1000][16][64]
                 double* __restrict__ dacc,           // [64]
                 int n_cuts, int n_frags, int ncc, int nblk_part) {
    int t = threadIdx.x;
    int bid = blockIdx.x;
    if (bid >= nblk_part) {
        int r = bid - nblk_part;
        if (r < 256) {
            // ---- lwprep: bf16 transpose [g][n][64], k-pads zeroed ----
            for (int g = r; g < G_; g += 256) {
                for (int i = t; i < L_ * K_; i += 256) {
                    float v = lw[(size_t)g * (L_ * K_) + i];
                    lwT[(size_t)g * 1024 + (i & 15) * 64 + (i >> 4)] =
                        __float2bfloat16(v);
                }
                for (int i = t; i < 16 * 14; i += 256) {
                    int n = i / 14, l = 50 + (i % 14);
                    lwT[(size_t)g * 1024 + n * 64 + l] = __float2bfloat16(0.f);
                }
            }
        } else {
            // ---- weight KL ----
            const int NTOT = G_ * L_ * K_ + G_ * L_;   // 850000
            int wb = r - 256;
            float s = 0.f;
            for (int i = wb * 256 + t; i < NTOT; i += 256 * 256) {
                float w = (i < G_ * L_ * K_) ? lw[i] : rw[i - G_ * L_ * K_];
                s += fmaf(-50.f * w, w, 1.3836465597893733f);
            }
            s = block_sum_256(s);
            if (t == 0) atomAddF64(&dacc[wb & 63], (double)(-s));
        }
        return;
    }
    // ---- radix partition, one 6144-record chunk per block ----
    __shared__ unsigned int cnt[1024], cur[1024], gbas[1024];
    __shared__ unsigned int wtot[4];
    __shared__ unsigned short stage[CHUNK_];
    __shared__ unsigned char bkof[CHUNK_];
    bool isCut = (bid < ncc);
    int blk = isCut ? bid : bid - ncc;
    const int* idx = isCut ? cut_ix : frag_ix;
    int n = isCut ? n_cuts : n_frags;
    unsigned int rcap = isCut ? RCAP_CUTQ : RCAP_FRAG;
    unsigned int* gcount = isCut ? gcnt_c : gcnt_f;
    unsigned short* ent = isCut ? entc : entf;
    int i0 = blk * CHUNK_;
    cnt[t] = 0; cnt[t + 256] = 0; cnt[t + 512] = 0; cnt[t + 768] = 0;
    // stage 24 records in registers: 6 int4 (+6 float4 for cuts), all in flight
    int4 I[6]; float4 X[6];
    unsigned int vm;
    bool full = (i0 + CHUNK_ <= n);
    if (full) {
        const int4* ip = (const int4*)(idx + i0);
#pragma unroll
        for (int k = 0; k < 6; ++k) I[k] = ip[k * 256 + t];
        if (isCut) {
            const float4* xp = (const float4*)(coord + i0);
#pragma unroll
            for (int k = 0; k < 6; ++k) X[k] = xp[k * 256 + t];
        }
        vm = 0xFFFFFFu;
    } else {
        vm = 0;
#pragma unroll
        for (int k = 0; k < 6; ++k) {
            int r0 = i0 + (k * 256 + t) * 4;
            int* Ii = (int*)&I[k]; float* Xi = (float*)&X[k];
#pragma unroll
            for (int u = 0; u < 4; ++u) {
                bool v = (r0 + u) < n;
                if (v) vm |= 1u << (k * 4 + u);
                Ii[u] = v ? idx[r0 + u] : 0;
                Xi[u] = (v && isCut) ? coord[r0 + u] : 0.f;
            }
        }
    }
    __syncthreads();
    // count
#pragma unroll
    for (int k = 0; k < 6; ++k) {
        const int* Ii = (const int*)&I[k];
        const float* Xi = (const float*)&X[k];
#pragma unroll
        for (int u = 0; u < 4; ++u) {
            if (vm & (1u << (k * 4 + u))) {
                int ix = Ii[u];
                int c = ix / G_;
                int g = ix - c * G_;
                unsigned int bk;
                if (isCut) {
                    int b = (int)(Xi[u] * 16.f); b = b > 15 ? 15 : b;
                    bk = ((unsigned)(c >> 6) << 6) | ((unsigned)(g * K_ + b) >> 8);
                } else {
                    bk = ((unsigned)(c >> 6) << 4) | ((unsigned)g >> 6);
                }
                atomicAdd(&cnt[bk], 1u);   // LDS atomic
            }
        }
    }
    __syncthreads();
    // exclusive prefix over 1024 bucket counts: 4/thread + 2-level wave scan
    {
        unsigned int c0 = cnt[t * 4 + 0], c1 = cnt[t * 4 + 1];
        unsigned int c2 = cnt[t * 4 + 2], c3 = cnt[t * 4 + 3];
        unsigned int tot = c0 + c1 + c2 + c3;
        unsigned int run = tot;
        int lane = t & 63, wv = t >> 6;
#pragma unroll
        for (int o = 1; o < 64; o <<= 1) {
            unsigned int v = __shfl_up(run, o, 64);
            if (lane >= o) run += v;
        }
        if (lane == 63) wtot[wv] = run;
        __syncthreads();
        unsigned int wb = 0;
#pragma unroll
        for (int w = 0; w < 3; ++w) if (w < wv) wb += wtot[w];
        unsigned int base = wb + run - tot;     // exclusive over 4-groups
        cur[t * 4 + 0] = base;
        cur[t * 4 + 1] = base + c0;
        cur[t * 4 + 2] = base + c0 + c1;
        cur[t * 4 + 3] = base + c0 + c1 + c2;
        // global reserve (returning atomics, spread addresses)
        gbas[t * 4 + 0] = c0 ? atomicAdd(&gcount[t * 4 + 0], c0) : 0u;
        gbas[t * 4 + 1] = c1 ? atomicAdd(&gcount[t * 4 + 1], c1) : 0u;
        gbas[t * 4 + 2] = c2 ? atomicAdd(&gcount[t * 4 + 2], c2) : 0u;
        gbas[t * 4 + 3] = c3 ? atomicAdd(&gcount[t * 4 + 3], c3) : 0u;
    }
    __syncthreads();
    // scatter from registers (cut e carries bk[9:8] in bits 15:14)
#pragma unroll
    for (int k = 0; k < 6; ++k) {
        const int* Ii = (const int*)&I[k];
        const float* Xi = (const float*)&X[k];
#pragma unroll
        for (int u = 0; u < 4; ++u) {
            if (vm & (1u << (k * 4 + u))) {
                int ix = Ii[u];
                int c = ix / G_;
                int g = ix - c * G_;
                unsigned int bk; unsigned short e;
                if (isCut) {
                    int b = (int)(Xi[u] * 16.f); b = b > 15 ? 15 : b;
                    int bin = g * K_ + b;
                    bk = ((unsigned)(c >> 6) << 6) | ((unsigned)bin >> 8);
                    e = (unsigned short)(((bk >> 8) << 14) |
                                         ((c & 63) << 8) | (bin & 255));
                } else {
                    bk = ((unsigned)(c >> 6) << 4) | ((unsigned)g >> 6);
                    e = (unsigned short)(((c & 63) << 6) | (g & 63));
                }
                unsigned int p = atomicAdd(&cur[bk], 1u);   // LDS atomic
                stage[p] = e;
                bkof[p] = (unsigned char)bk;
            }
        }
    }
    __syncthreads();
    int total = n - i0; if (total > CHUNK_) total = CHUNK_;
    for (int p = t; p < total; p += 256) {
        unsigned int e = stage[p];
        unsigned int bk = ((e >> 14) << 8) | bkof[p];
        unsigned int beg = cur[bk] - cnt[bk];       // excl recomputed
        unsigned int dst = gbas[bk] + (p - beg);
        if (dst < rcap)
            ent[(size_t)bk * rcap + dst] = (unsigned short)e;
    }
}

// --- 2. mid kernel: [0,1024) quarter-bucket hist+enc | [1024,1280) frag ----
// r17: quarter-buckets pre-split by part => zero discard; hist 8KB; the
// reduction scratch overlays dead w1s => 24KB LDS total.
__global__ __launch_bounds__(256)
void mid_kernel(const unsigned int* __restrict__ gcnt_c,
                const unsigned short* __restrict__ entc,
                const unsigned int* __restrict__ gcnt_f,
                const unsigned short* __restrict__ entf,
                const float* __restrict__ W1,        // [16000][16]
                unsigned int* __restrict__ merged,   // [16000][128]
                unsigned int* __restrict__ fragw,    // u8[1000][1024] as u32
                float* __restrict__ hT) {            // [16][1024], pre-zeroed
    __shared__ unsigned int h[2048];   // 8 KB nibble hist
    __shared__ float w1s[4096];        // 16 KB W1 stage; reused as reduction sp
    int t = threadIdx.x;
    int bid = blockIdx.x;
    if (bid < 1024) {
        // ---- one quarter-bucket: 256 bins x 64 cells ----
        int bk = bid;
        int cg = bk >> 6, bgrp = bk & 63;
        int wbase = (bgrp * 256) * NHID_;
#pragma unroll
        for (int r = 0; r < 16; ++r) {
            int i = r * 256 + t;
            int gi = wbase + i;
            w1s[i] = (gi < 16000 * NHID_) ? W1[gi] : 0.f;
        }
        for (int i = t; i < 2048; i += 256) h[i] = 0;
        __syncthreads();
        unsigned int count = gcnt_c[bk];
        if (count > RCAP_CUTQ) count = RCAP_CUTQ;
        const unsigned int* e32 = (const unsigned int*)(entc + (size_t)bk * RCAP_CUTQ);
        unsigned int npair = count >> 1;
        for (unsigned int base = 0; base < npair; base += 1024) {
            unsigned int w[4]; bool val[4];
#pragma unroll
            for (int u = 0; u < 4; ++u) {
                unsigned int p = base + u * 256 + t;
                val[u] = (p < npair);
                w[u] = val[u] ? e32[p] : 0u;
            }
#pragma unroll
            for (int u = 0; u < 4; ++u) {
                if (val[u]) {
                    unsigned int v0 = w[u] & 0xffffu, v1 = w[u] >> 16;
                    unsigned int c0 = (v0 >> 8) & 63u, c1 = (v1 >> 8) & 63u;
                    atomicAdd(&h[(v0 & 255u) * 8 + (c0 >> 3)],
                              1u << ((c0 & 7) * 4));
                    atomicAdd(&h[(v1 & 255u) * 8 + (c1 >> 3)],
                              1u << ((c1 & 7) * 4));
                }
            }
        }
        if (t == 0 && (count & 1u)) {
            unsigned int v = ((const unsigned short*)e32)[count - 1];
            unsigned int c0 = (v >> 8) & 63u;
            atomicAdd(&h[(v & 255u) * 8 + (c0 >> 3)], 1u << ((c0 & 7) * 4));
        }
        __syncthreads();
        for (int i = t; i < 2048; i += 256) {
            int bin = bgrp * 256 + (i >> 3);
            if (bin < 16000)
                merged[(unsigned)bin * 128u + (unsigned)cg * 8u + (i & 7)] = h[i];
        }
        // enc: W1 from LDS broadcast
        int c_lo = t & 63, sub = t >> 6;
        float acc[NHID_];
#pragma unroll
        for (int j = 0; j < NHID_; ++j) acc[j] = 0.f;
        int rbase = bgrp * 256 + sub * 64;
        int sh = (c_lo & 7) * 4;
        const float4* w1v = (const float4*)w1s;
#pragma unroll 2
        for (int bl = 0; bl < 64; ++bl) {
            int row = rbase + bl;
            if (row < 16000) {   // wave-uniform
                int rl = sub * 64 + bl;
                unsigned int w = h[rl * 8 + (c_lo >> 3)];
                float xv = __logf((float)(((w >> sh) & 0xfu) + 1u));
                float4 wa = w1v[rl * 4 + 0];
                float4 wb = w1v[rl * 4 + 1];
                float4 wc = w1v[rl * 4 + 2];
                float4 wd = w1v[rl * 4 + 3];
                acc[0] = fmaf(xv, wa.x, acc[0]);  acc[1] = fmaf(xv, wa.y, acc[1]);
                acc[2] = fmaf(xv, wa.z, acc[2]);  acc[3] = fmaf(xv, wa.w, acc[3]);
                acc[4] = fmaf(xv, wb.x, acc[4]);  acc[5] = fmaf(xv, wb.y, acc[5]);
                acc[6] = fmaf(xv, wb.z, acc[6]);  acc[7] = fmaf(xv, wb.w, acc[7]);
                acc[8] = fmaf(xv, wc.x, acc[8]);  acc[9] = fmaf(xv, wc.y, acc[9]);
                acc[10] = fmaf(xv, wc.z, acc[10]); acc[11] = fmaf(xv, wc.w, acc[11]);
                acc[12] = fmaf(xv, wd.x, acc[12]); acc[13] = fmaf(xv, wd.y, acc[13]);
                acc[14] = fmaf(xv, wd.z, acc[14]); acc[15] = fmaf(xv, wd.w, acc[15]);
            }
        }
        __syncthreads();               // w1s dead from here; reuse as sp
        float* sp = (float*)w1s;
#pragma unroll
        for (int j = 0; j < NHID_; ++j) sp[sub * 1024 + j * 64 + c_lo] = acc[j];
        __syncthreads();
        for (int i = t; i < 1024; i += 256) {
            int j = i >> 6, c = i & 63;
            float v = sp[j * 64 + c] + sp[1024 + j * 64 + c]
                    + sp[2048 + j * 64 + c] + sp[3072 + j * 64 + c];
            atomicAdd(&hT[j * C_ + cg * 64 + c], v);   // fire-and-forget f32
        }
    } else {
        // ---- per-bucket frag counts -> u8 ----
        int bk = bid - 1024, cg = bk >> 4, gc = bk & 15;
        for (int i = t; i < 2048; i += 256) h[i] = 0;
        __syncthreads();
        unsigned int count = gcnt_f[bk];
        if (count > RCAP_FRAG) count = RCAP_FRAG;
        const unsigned short* e = entf + (size_t)bk * RCAP_FRAG;
#pragma unroll 4
        for (unsigned int p = t; p < count; p += 256) {
            unsigned int v = e[p];
            unsigned int g_lo = v & 63u;
            unsigned int c_lo = (v >> 6) & 63u;
            atomicAdd(&h[g_lo * 32 + (c_lo >> 1)], 1u << ((c_lo & 1) * 16));
        }
        __syncthreads();
        for (int i = t; i < 1024; i += 256) {
            int g_lo = i >> 4, wb = i & 15;
            unsigned int lo = h[g_lo * 32 + wb * 2];
            unsigned int hi = h[g_lo * 32 + wb * 2 + 1];
            unsigned int outv = (lo & 0xffu) | (((lo >> 16) & 0xffu) << 8)
                              | ((hi & 0xffu) << 16) | (((hi >> 16) & 0xffu) << 24);
            int g = gc * 64 + g_lo;
            if (g < G_)
                fragw[(unsigned)g * 256u + (unsigned)cg * 16u + wb] = outv;
        }
    }
}

// --- 3. latent: BN stats from hT (f64, per block) + sample + KL ------------
__global__ __launch_bounds__(256)
void latent_kernel(const float* __restrict__ hT,     // [16][1024]
                   const float* __restrict__ gamma,
                   const float* __restrict__ beta,
                   const float* __restrict__ W_loc,   // [16][50]
                   const float* __restrict__ b_loc,
                   const float* __restrict__ W_scale, // [16][50]
                   const float* __restrict__ b_scale,
                   const float* __restrict__ eps,     // [1024][50]
                   float* __restrict__ latT,          // [50][1024]
                   __hip_bfloat16* __restrict__ latbf,// [1024][64]
                   double* __restrict__ dacc) {       // [64]
    __shared__ float scs[NHID_], shs[NHID_];
    int t = threadIdx.x;
    {   // phase 1: per-block redundant BN stats (hT is 64 KB, L2-hot)
        int j = t >> 4, cl = t & 15;
        double s1 = 0.0, s2 = 0.0;
#pragma unroll 8
        for (int k = 0; k < 64; ++k) {
            float v = hT[j * C_ + cl + k * 16];
            s1 += (double)v; s2 += (double)v * (double)v;
        }
#pragma unroll
        for (int m = 1; m < 16; m <<= 1) {   // reduce 16-lane groups (same j)
            s1 += __shfl_xor(s1, m);
            s2 += __shfl_xor(s2, m);
        }
        if (cl == 0) {
            double mean = s1 * (1.0 / C_);
            double var = s2 * (1.0 / C_) - mean * mean;
            float rstd = rsqrtf((float)var + 1e-5f);
            float sc = gamma[j] * rstd;
            scs[j] = sc;
            shs[j] = beta[j] - (float)mean * sc;
        }
    }
    __syncthreads();
    int idx = blockIdx.x * 256 + t;
    float kl = 0.f;
    {
        int c = idx / L_;
        int l = idx - c * L_;
        float hb[NHID_];
#pragma unroll
        for (int j = 0; j < NHID_; ++j) {
            float v = fmaf(hT[j * C_ + c], scs[j], shs[j]);
            hb[j] = v > 0.f ? v : 0.f;
        }
        float loc = b_loc[l], ls = b_scale[l];
#pragma unroll
        for (int j = 0; j < NHID_; ++j) {
            loc = fmaf(hb[j], W_loc[j * L_ + l], loc);
            ls  = fmaf(hb[j], W_scale[j * L_ + l], ls);
        }
        float qs = 0.1f * __expf(ls);
        float e = eps[idx];
        float lat = fmaf(qs, e, loc);
        latT[(size_t)l * C_ + c] = lat;
        latbf[c * 64 + l] = __float2bfloat16(lat);
        if (l < 14) latbf[c * 64 + 50 + l] = __float2bfloat16(0.f);  // k-pad
        float z = (lat - loc) / qs;
        kl = fmaf(-0.5f * lat, lat, fmaf(0.5f * z, z, __logf(qs)));
    }
    float s = block_sum_256(kl);
    if (threadIdx.x == 0)
        atomAddF64(&dacc[blockIdx.x & 63], (double)(-CELL_SCALE * s));
}

// --- 4. mixture (swapped-operand MFMA, lane-local softmax) + Poisson -------
// grid (1000, 4): block (g, y) does mixture AND Poisson for cells
// [y*256, y*256+256). D = lwT x latbf^T => lane holds 4 comps of ONE cell.
__global__ __launch_bounds__(256)
void mixpois_kernel(const __hip_bfloat16* __restrict__ latbf, // [1024][64]
                    const __hip_bfloat16* __restrict__ lwT,   // [1000][16][64]
                    const unsigned int* __restrict__ merged,  // [16000][128]
                    const float* __restrict__ baseline,       // [1000][16]
                    const float* __restrict__ latT,           // [50][1024]
                    const float* __restrict__ rw,             // [1000][50]
                    const float* __restrict__ rho_bias,
                    const int* __restrict__ libsize,
                    const unsigned char* __restrict__ fragb,  // [1000][1024]
                    double* __restrict__ dacc,                // [64]
                    unsigned int* __restrict__ done,          // zeroed
                    float* __restrict__ out) {
    int g = blockIdx.x;
    int y = blockIdx.y;
    int t = threadIdx.x;
    int lane = t & 63;
    int wv = t >> 6;
    int s16 = lane & 15;           // A row sel (comp) AND B col sel (cell)
    int quad = lane >> 4;
    const __hip_bfloat16* bb = lwT + (size_t)g * 1024 + s16 * 64 + quad * 8;
    short8 lw1 = *(const short8*)bb;
    short8 lw2 = *(const short8*)(bb + 32);
    const float4 bl4 = *(const float4*)(baseline + g * K_ + quad * 4);
    const unsigned int* mrow =
        merged + (size_t)(g * K_ + quad * 4) * 128u;   // +r*128 per reg
    float partial = 0.f;
    int cwave = y * 256 + wv * 64;
#pragma unroll
    for (int mt = 0; mt < 4; ++mt) {
        int c0 = cwave + mt * 16;
        const __hip_bfloat16* aa = latbf + (size_t)(c0 + s16) * 64 + quad * 8;
        short8 la1 = *(const short8*)aa;
        short8 la2 = *(const short8*)(aa + 32);
        f32x4 d = {bl4.x, bl4.y, bl4.z, bl4.w};
        d = __builtin_amdgcn_mfma_f32_16x16x32_bf16(lw1, la1, d, 0, 0, 0);
        d = __builtin_amdgcn_mfma_f32_16x16x32_bf16(lw2, la2, d, 0, 0, 0);
        float m = fmaxf(fmaxf(d[0], d[1]), fmaxf(d[2], d[3]));
        m = fmaxf(m, __shfl_xor(m, 16));
        m = fmaxf(m, __shfl_xor(m, 32));
        float e0 = __expf(d[0] - m), e1 = __expf(d[1] - m);
        float e2 = __expf(d[2] - m), e3 = __expf(d[3] - m);
        float S = (e0 + e1) + (e2 + e3);
        S += __shfl_xor(S, 16);
        S += __shfl_xor(S, 32);
        float lse = m + __logf(S);
        int cp = c0 + s16;
        unsigned int widx = (unsigned)cp >> 3;
        int sb = (cp & 7) * 4;
#pragma unroll
        for (int r = 0; r < 4; ++r) {
            float cnt = (float)((mrow[r * 128u + widx] >> sb) & 0xfu);
            partial = fmaf(cnt, d[r] - lse, partial);
        }
    }
    // ---- Poisson for the same cell tile ----
    float v;
    {
        int c = y * 256 + t;
        const float* rwg = rw + (size_t)g * L_;   // hoists to SGPRs
        float rho = 0.f;
#pragma unroll 10
        for (int l = 0; l < L_; ++l)
            rho = fmaf(latT[l * C_ + c], rwg[l], rho);
        unsigned int fc = fragb[(size_t)g * C_ + c];
        float fe = rho_bias[g] * __expf(rho) * (float)libsize[c];
        float lf = fmaf((float)fc, __logf(fe), -fe) - LGT[fc > 31u ? 31u : fc];
        v = fmaf(-CUT_SCALE, partial, -CELL_SCALE * lf);
    }
    float contrib = block_sum_256(v);
    // ---- fence-free fused final: atomic f64 accumulate + 2-level counter --
    __shared__ int lastflag;
    if (threadIdx.x == 0) {
        lastflag = 0;
        int slot = blockIdx.x & 63;
        double oldv = atomAddF64(&dacc[slot], (double)contrib);
        unsigned inc = 1u;
        float dep = (float)oldv;
        asm volatile("" : "+v"(inc) : "v"(dep));
        unsigned quota = ((slot < 40) ? 16u : 15u) * 4u;   // 1000 = 15*64+40
        if (atomicAdd(&done[slot * 16], inc) == quota - 1u) {
            if (atomicAdd(&done[1024], 1u) == 63u) lastflag = 1;
        }
    }
    __syncthreads();
    if (lastflag) {
        if (t < 64) {
            double dv = atomAddF64(&dacc[t], 0.0);
#pragma unroll
            for (int m = 1; m < 64; m <<= 1) dv += __shfl_xor(dv, m);
            if (t == 0)
                out[0] = (float)(dv - 138629436.11198905); // -12.5*4e6*log16
        }
    }
}

extern "C" void kernel_launch(void* const* d_in, const int* in_sizes, int n_in,
                              void* d_out, int out_size, void* d_ws, size_t ws_size,
                              hipStream_t stream) {
    const float* cut_coord = (const float*)d_in[0];
    const float* eps       = (const float*)d_in[1];
    const float* enc_W1    = (const float*)d_in[2];
    // d_in[3] = enc_b1 : cancels through BatchNorm, unused
    const float* bn_gamma  = (const float*)d_in[4];
    const float* bn_beta   = (const float*)d_in[5];
    const float* W_loc     = (const float*)d_in[6];
    const float* b_loc     = (const float*)d_in[7];
    const float* W_scale   = (const float*)d_in[8];
    const float* b_scale   = (const float*)d_in[9];
    const float* logit_w   = (const float*)d_in[10];
    const float* rho_w     = (const float*)d_in[11];
    const float* baseline  = (const float*)d_in[12];
    const float* rho_bias  = (const float*)d_in[13];
    const int* cut_cxg     = (const int*)d_in[14];
    const int* frag_ix     = (const int*)d_in[16];
    const int* libsize     = (const int*)d_in[19];

    int n_cuts  = in_sizes[0];
    int n_frags = in_sizes[16];

    char* ws = (char*)d_ws;
    unsigned int*   gcnt_c = (unsigned int*)(ws + GCNTC_OFF);
    unsigned int*   gcnt_f = (unsigned int*)(ws + GCNTF_OFF);
    unsigned int*   done   = (unsigned int*)(ws + DONE_OFF);
    double*         dacc   = (double*)(ws + DACC_OFF);
    float*          hT     = (float*)(ws + HT_OFF);
    __hip_bfloat16* latbf  = (__hip_bfloat16*)(ws + LATBF_OFF);
    __hip_bfloat16* lwT    = (__hip_bfloat16*)(ws + LWT_OFF);
    unsigned short* entc   = (unsigned short*)(ws + ENTC_OFF);
    unsigned short* entf   = (unsigned short*)(ws + ENTF_OFF);
    unsigned int*   merged = (unsigned int*)(ws + MERGED_OFF);
    unsigned int*   fragw  = (unsigned int*)(ws + FRAGU8_OFF);
    float*          latT   = (float*)(ws + LATT_OFF);
    float*          out    = (float*)d_out;

    int ncc = (n_cuts + CHUNK_ - 1) / CHUNK_;
    int ncf = (n_frags + CHUNK_ - 1) / CHUNK_;
    int nblk_part = ncc + ncf;

    hipMemsetAsync(ws, 0, ZERO_BYTES, stream);   // gcnt + done + dacc + hT

    part_kernel<<<nblk_part + 512, 256, 0, stream>>>(
        cut_cxg, cut_coord, frag_ix, gcnt_c, gcnt_f, entc, entf,
        logit_w, rho_w, lwT, dacc,
        n_cuts, n_frags, ncc, nblk_part);
    mid_kernel<<<1280, 256, 0, stream>>>(
        gcnt_c, entc, gcnt_f, entf, enc_W1, merged, fragw, hT);
    latent_kernel<<<(C_ * L_) / 256, 256, 0, stream>>>(
        hT, bn_gamma, bn_beta, W_loc, b_loc, W_scale, b_scale,
        eps, latT, latbf, dacc);
    mixpois_kernel<<<dim3(G_, 4), 256, 0, stream>>>(
        latbf, lwT, merged, baseline, latT, rho_w, rho_bias, libsize,
        (const unsigned char*)fragw, dacc, done, out);
}

// Round 5
// 244.517 us; speedup vs baseline: 1.0230x; 1.0230x over previous
//
#include <hip/hip_runtime.h>
#include <hip/hip_bf16.h>
#include <math.h>

// ---------------------------------------------------------------------------
// VAE ELBO (chromatin VAE). Sizes fixed by the reference.
//
//  * NB_ENC == NB_DEC == 16, identical binning => ONE nibble histogram serves
//    both the encoder input (log1p counts) and the mixture likelihood.
//  * r3-r5: global per-record atomics too slow => two-phase LDS counting sort.
//  * r7: same-address atomics serialize ~16ns => per-block partial stores.
//  * r8: roles fused as block-ranges.
//  * r12: hipLaunchCooperativeKernel DOES NOT RUN under this harness.
//  * r13: part = register-staged single pass; mid = hist+enc / frag only.
//  * r14: __threadfence = L2 wb/inv on 8 non-coherent XCD L2s => +138us. BAN.
//  * r15: fence-free tail: f64 atomics into dacc[64]; returning-atomic
//    data-dep orders done-counter. mixpois 179->52.6.
//  * r16: swapped-operand MFMA => lane-local softmax (mixpois off top-5);
//    Poisson fused into mixture blocks, grid (1000,4). BEST so far structure.
//  * r17: 1024-bucket partition REGRESSED part 41->73 (6-entry runs => 4x
//    write amplification, 42MB WRITE_SIZE; occupancy 7->5). REVERTED.
//  * r18 (this round): quarter-split moved to the CONSUMER instead: mid cut
//    blocks now own a FULL bucket (256 blocks) with the whole 1024-bin x
//    64-cell nibble hist in 32KB LDS => each entc entry read ONCE (r16 read
//    4x, discarding 3/4 after unpack+compare). Encoder runs in 4 chunks of
//    256 rows, staging 16KB W1 per chunk; w1s reused as reduction scratch.
//    LDS 48KB, grid 512 (2 blocks/CU, uniform buckets).
// ---------------------------------------------------------------------------

#define G_      1000
#define C_      1024
#define L_      50
#define K_      16
#define NHID_   16
#define CUT_SCALE   12.5f          // N_TOTAL_CUTS / N_CUTS
#define CELL_SCALE  9.765625f      // N_TOTAL_CELLS / N_CELLS

#define CHUNK_    6144
#define RCAP_CUT  18432            // bucket capacity, cuts  (mean 16000)
#define RCAP_FRAG 9216             // bucket capacity, frags (mean 8000)

// ws layout (bytes); [0, ZERO_BYTES) memset per call (gcnt + done + dacc + hT).
#define GCNTC_OFF  0ull
#define GCNTF_OFF  1024ull
#define DONE_OFF   2048ull         // u32: 64 slots @ stride 16 u32, lvl2 @ [1024]
#define DACC_OFF   6400ull         // f64[64] global ELBO accumulator slots
#define HT_OFF     6912ull         // f32 [16][1024] (atomic-accumulated by mid)
#define ZERO_BYTES 72448ull
#define LATBF_OFF  72448ull        // bf16 [1024][64]
#define LWT_OFF    203520ull       // bf16 [1000][16][64]
#define ENTC_OFF   2251520ull      // u16 [256][18432]
#define ENTF_OFF   11688704ull     // u16 [256][9216]
#define MERGED_OFF 16407296ull     // u32 [16000][128] nibble hist
#define FRAGU8_OFF 24599296ull     // u8  [1000][1024]
#define LATT_OFF   25623296ull     // f32 [50][1024]
#define WS_NEED    25828096ull

typedef __attribute__((ext_vector_type(8))) short short8;
typedef __attribute__((ext_vector_type(4))) float f32x4;

__device__ __constant__ float LGT[32] = {   // log(n!)
    0.0f, 0.0f, 0.6931471805599453f, 1.791759469228055f, 3.1780538303479458f,
    4.787491742782046f, 6.579251212010101f, 8.525161361065415f,
    10.60460290274525f, 12.801827480081469f, 15.104412573075516f,
    17.502307845873887f, 19.987214495661885f, 22.552163853123425f,
    25.19122118273868f, 27.89927138384089f, 30.671860106080672f,
    33.50507345013689f, 36.39544520803305f, 39.339884187199495f,
    42.335616460753485f, 45.38013889847691f, 48.47118135183523f,
    51.60667556776438f, 54.78472939811232f, 58.00360522298052f,
    61.261701761002f, 64.55753862700633f, 67.88974313718154f,
    71.25703896716801f, 74.65823634883016f, 78.0922235533153f };

// f64 atomic add at the device coherent point (returns old value; the return
// is used to fabricate ordering dependencies — NO fences anywhere).
__device__ __forceinline__ double atomAddF64(double* p, double v) {
    return __hip_atomic_fetch_add(p, v, __ATOMIC_RELAXED,
                                  __HIP_MEMORY_SCOPE_AGENT);
}

__device__ __forceinline__ float block_sum_256(float v) {
    __shared__ float sm[256];
    int t = threadIdx.x;
    __syncthreads();
    sm[t] = v;
    __syncthreads();
#pragma unroll
    for (int s = 128; s > 0; s >>= 1) {
        if (t < s) sm[t] += sm[t + s];
        __syncthreads();
    }
    return sm[0];
}

// --- 1. part: [0,nblk_part) radix partition (register-staged single pass) |
//        [nblk_part, +256) lwprep | [+256, +512) wkl ------------------------
__global__ __launch_bounds__(256)
void part_kernel(const int* __restrict__ cut_ix,
                 const float* __restrict__ coord,
                 const int* __restrict__ frag_ix,
                 unsigned int* __restrict__ gcnt_c,
                 unsigned int* __restrict__ gcnt_f,
                 unsigned short* __restrict__ entc,
                 unsigned short* __restrict__ entf,
                 const float* __restrict__ lw,      // [1000][50][16]
                 const float* __restrict__ rw,      // [1000][50]
                 __hip_bfloat16* __restrict__ lwT,  // [1000][16][64]
                 double* __restrict__ dacc,         // [64]
                 int n_cuts, int n_frags, int ncc, int nblk_part) {
    int t = threadIdx.x;
    int bid = blockIdx.x;
    if (bid >= nblk_part) {
        int r = bid - nblk_part;
        if (r < 256) {
            // ---- lwprep: bf16 transpose [g][n][64], k-pads zeroed ----
            for (int g = r; g < G_; g += 256) {
                for (int i = t; i < L_ * K_; i += 256) {
                    float v = lw[(size_t)g * (L_ * K_) + i];
                    lwT[(size_t)g * 1024 + (i & 15) * 64 + (i >> 4)] =
                        __float2bfloat16(v);
                }
                for (int i = t; i < 16 * 14; i += 256) {
                    int n = i / 14, l = 50 + (i % 14);
                    lwT[(size_t)g * 1024 + n * 64 + l] = __float2bfloat16(0.f);
                }
            }
        } else {
            // ---- weight KL ----
            const int NTOT = G_ * L_ * K_ + G_ * L_;   // 850000
            int wb = r - 256;
            float s = 0.f;
            for (int i = wb * 256 + t; i < NTOT; i += 256 * 256) {
                float w = (i < G_ * L_ * K_) ? lw[i] : rw[i - G_ * L_ * K_];
                s += fmaf(-50.f * w, w, 1.3836465597893733f);
            }
            s = block_sum_256(s);
            if (t == 0) atomAddF64(&dacc[wb & 63], (double)(-s));
        }
        return;
    }
    // ---- radix partition, one 6144-record chunk per block ----
    __shared__ unsigned int cnt[256], excl[256], cur[256], gbas[256];
    __shared__ unsigned short stage[CHUNK_];
    __shared__ unsigned char bkof[CHUNK_];
    bool isCut = (bid < ncc);
    int blk = isCut ? bid : bid - ncc;
    const int* idx = isCut ? cut_ix : frag_ix;
    int n = isCut ? n_cuts : n_frags;
    int rcap = isCut ? RCAP_CUT : RCAP_FRAG;
    unsigned int* gcount = isCut ? gcnt_c : gcnt_f;
    unsigned short* ent = isCut ? entc : entf;
    int i0 = blk * CHUNK_;
    cnt[t] = 0;
    // stage 24 records in registers: 6 int4 (+6 float4 for cuts), all in flight
    int4 I[6]; float4 X[6];
    unsigned int vm;
    bool full = (i0 + CHUNK_ <= n);
    if (full) {
        const int4* ip = (const int4*)(idx + i0);
#pragma unroll
        for (int k = 0; k < 6; ++k) I[k] = ip[k * 256 + t];
        if (isCut) {
            const float4* xp = (const float4*)(coord + i0);
#pragma unroll
            for (int k = 0; k < 6; ++k) X[k] = xp[k * 256 + t];
        }
        vm = 0xFFFFFFu;
    } else {
        vm = 0;
#pragma unroll
        for (int k = 0; k < 6; ++k) {
            int r0 = i0 + (k * 256 + t) * 4;
            int* Ii = (int*)&I[k]; float* Xi = (float*)&X[k];
#pragma unroll
            for (int u = 0; u < 4; ++u) {
                bool v = (r0 + u) < n;
                if (v) vm |= 1u << (k * 4 + u);
                Ii[u] = v ? idx[r0 + u] : 0;
                Xi[u] = (v && isCut) ? coord[r0 + u] : 0.f;
            }
        }
    }
    __syncthreads();
    // count
#pragma unroll
    for (int k = 0; k < 6; ++k) {
        const int* Ii = (const int*)&I[k];
        const float* Xi = (const float*)&X[k];
#pragma unroll
        for (int u = 0; u < 4; ++u) {
            if (vm & (1u << (k * 4 + u))) {
                int ix = Ii[u];
                int c = ix / G_;
                int g = ix - c * G_;
                unsigned int bk;
                if (isCut) {
                    int b = (int)(Xi[u] * 16.f); b = b > 15 ? 15 : b;
                    bk = ((unsigned)(c >> 6) << 4) | ((unsigned)(g * K_ + b) >> 10);
                } else {
                    bk = ((unsigned)(c >> 6) << 4) | ((unsigned)g >> 6);
                }
                atomicAdd(&cnt[bk], 1u);   // LDS atomic
            }
        }
    }
    __syncthreads();
    // exclusive prefix over 256 bucket counts, single wave, shfl scan
    if (t < 64) {
        unsigned int c0 = cnt[t * 4 + 0], c1 = cnt[t * 4 + 1];
        unsigned int c2 = cnt[t * 4 + 2], c3 = cnt[t * 4 + 3];
        unsigned int tot = c0 + c1 + c2 + c3;
        unsigned int run = tot;
#pragma unroll
        for (int o = 1; o < 64; o <<= 1) {
            unsigned int v = __shfl_up(run, o, 64);
            if (t >= o) run += v;
        }
        unsigned int base = run - tot;          // exclusive over 4-groups
        excl[t * 4 + 0] = base;
        excl[t * 4 + 1] = base + c0;
        excl[t * 4 + 2] = base + c0 + c1;
        excl[t * 4 + 3] = base + c0 + c1 + c2;
    }
    __syncthreads();
    gbas[t] = cnt[t] ? atomicAdd(&gcount[t], cnt[t]) : 0u;  // global reserve
    cur[t] = excl[t];
    __syncthreads();
    // scatter from registers
#pragma unroll
    for (int k = 0; k < 6; ++k) {
        const int* Ii = (const int*)&I[k];
        const float* Xi = (const float*)&X[k];
#pragma unroll
        for (int u = 0; u < 4; ++u) {
            if (vm & (1u << (k * 4 + u))) {
                int ix = Ii[u];
                int c = ix / G_;
                int g = ix - c * G_;
                unsigned int bk; unsigned short e;
                if (isCut) {
                    int b = (int)(Xi[u] * 16.f); b = b > 15 ? 15 : b;
                    int bin = g * K_ + b;
                    bk = ((unsigned)(c >> 6) << 4) | ((unsigned)bin >> 10);
                    e = (unsigned short)(((c & 63) << 10) | (bin & 1023));
                } else {
                    bk = ((unsigned)(c >> 6) << 4) | ((unsigned)g >> 6);
                    e = (unsigned short)(((c & 63) << 6) | (g & 63));
                }
                unsigned int p = atomicAdd(&cur[bk], 1u);   // LDS atomic
                stage[p] = e;
                bkof[p] = (unsigned char)bk;
            }
        }
    }
    __syncthreads();
    int total = n - i0; if (total > CHUNK_) total = CHUNK_;
    for (int p = t; p < total; p += 256) {
        unsigned int bk = bkof[p];
        unsigned int dst = gbas[bk] + (p - excl[bk]);
        if (dst < (unsigned)rcap)
            ent[(size_t)bk * rcap + dst] = stage[p];
    }
}

// --- 2. mid kernel: [0,256) FULL-bucket hist+enc | [256,512) frag ----------
// r18: one block per full cut bucket; 32KB hist (1024 bins x 64 cells) =>
// each entc entry read once. Encoder in 4 chunks of 256 rows with 16KB W1
// staging; w1s reused as reduction scratch. LDS 48KB.
__global__ __launch_bounds__(256)
void mid_kernel(const unsigned int* __restrict__ gcnt_c,
                const unsigned short* __restrict__ entc,
                const unsigned int* __restrict__ gcnt_f,
                const unsigned short* __restrict__ entf,
                const float* __restrict__ W1,        // [16000][16]
                unsigned int* __restrict__ merged,   // [16000][128]
                unsigned int* __restrict__ fragw,    // u8[1000][1024] as u32
                float* __restrict__ hT) {            // [16][1024], pre-zeroed
    __shared__ unsigned int h[8192];   // 32 KB nibble hist
    __shared__ float w1s[4096];        // 16 KB W1 chunk stage / reduction sp
    int t = threadIdx.x;
    int bid = blockIdx.x;
    if (bid < 256) {
        // ---- full bucket: 1024 bins x 64 cells ----
        int bk = bid;
        int cg = bk >> 4, bc = bk & 15;
        for (int i = t; i < 8192; i += 256) h[i] = 0;
        __syncthreads();
        unsigned int count = gcnt_c[bk];
        if (count > RCAP_CUT) count = RCAP_CUT;
        const unsigned int* e32 = (const unsigned int*)(entc + (size_t)bk * RCAP_CUT);
        unsigned int npair = count >> 1;
        for (unsigned int base = 0; base < npair; base += 1024) {
            unsigned int w[4]; bool val[4];
#pragma unroll
            for (int u = 0; u < 4; ++u) {
                unsigned int p = base + u * 256 + t;
                val[u] = (p < npair);
                w[u] = val[u] ? e32[p] : 0u;
            }
#pragma unroll
            for (int u = 0; u < 4; ++u) {
                if (val[u]) {
                    unsigned int v0 = w[u] & 0xffffu, v1 = w[u] >> 16;
                    unsigned int c0 = v0 >> 10, c1 = v1 >> 10;
                    atomicAdd(&h[(v0 & 1023u) * 8 + (c0 >> 3)],
                              1u << ((c0 & 7) * 4));
                    atomicAdd(&h[(v1 & 1023u) * 8 + (c1 >> 3)],
                              1u << ((c1 & 7) * 4));
                }
            }
        }
        if (t == 0 && (count & 1u)) {
            unsigned int v = ((const unsigned short*)e32)[count - 1];
            unsigned int c0 = v >> 10;
            atomicAdd(&h[(v & 1023u) * 8 + (c0 >> 3)], 1u << ((c0 & 7) * 4));
        }
        __syncthreads();
        for (int i = t; i < 8192; i += 256) {
            int bin = bc * 1024 + (i >> 3);
            if (bin < 16000)
                merged[(unsigned)bin * 128u + (unsigned)cg * 8u + (i & 7)] = h[i];
        }
        // ---- encoder over 1024 rows, 4 chunks of 256 with W1 staging ----
        int c_lo = t & 63, sub = t >> 6;
        float acc[NHID_];
#pragma unroll
        for (int j = 0; j < NHID_; ++j) acc[j] = 0.f;
        int sh = (c_lo & 7) * 4;
        for (int qq = 0; qq < 4; ++qq) {
            __syncthreads();               // prev chunk's w1s reads done
            int wbase = (bc * 1024 + qq * 256) * NHID_;
#pragma unroll
            for (int r = 0; r < 16; ++r) {
                int i = r * 256 + t;
                int gi = wbase + i;
                w1s[i] = (gi < 16000 * NHID_) ? W1[gi] : 0.f;
            }
            __syncthreads();
            const float4* w1v = (const float4*)w1s;
            int rl0 = qq * 256 + sub * 64;
#pragma unroll 2
            for (int bl = 0; bl < 64; ++bl) {
                int row = bc * 1024 + rl0 + bl;
                if (row < 16000) {   // wave-uniform
                    int rh = rl0 + bl;           // hist row 0..1023
                    int rw2 = sub * 64 + bl;     // w1s row 0..255
                    unsigned int w = h[rh * 8 + (c_lo >> 3)];
                    float xv = __logf((float)(((w >> sh) & 0xfu) + 1u));
                    float4 wa = w1v[rw2 * 4 + 0];
                    float4 wb = w1v[rw2 * 4 + 1];
                    float4 wc = w1v[rw2 * 4 + 2];
                    float4 wd = w1v[rw2 * 4 + 3];
                    acc[0] = fmaf(xv, wa.x, acc[0]);  acc[1] = fmaf(xv, wa.y, acc[1]);
                    acc[2] = fmaf(xv, wa.z, acc[2]);  acc[3] = fmaf(xv, wa.w, acc[3]);
                    acc[4] = fmaf(xv, wb.x, acc[4]);  acc[5] = fmaf(xv, wb.y, acc[5]);
                    acc[6] = fmaf(xv, wb.z, acc[6]);  acc[7] = fmaf(xv, wb.w, acc[7]);
                    acc[8] = fmaf(xv, wc.x, acc[8]);  acc[9] = fmaf(xv, wc.y, acc[9]);
                    acc[10] = fmaf(xv, wc.z, acc[10]); acc[11] = fmaf(xv, wc.w, acc[11]);
                    acc[12] = fmaf(xv, wd.x, acc[12]); acc[13] = fmaf(xv, wd.y, acc[13]);
                    acc[14] = fmaf(xv, wd.z, acc[14]); acc[15] = fmaf(xv, wd.w, acc[15]);
                }
            }
        }
        __syncthreads();               // w1s dead; reuse as reduction sp
        float* sp = (float*)w1s;
#pragma unroll
        for (int j = 0; j < NHID_; ++j) sp[sub * 1024 + j * 64 + c_lo] = acc[j];
        __syncthreads();
        for (int i = t; i < 1024; i += 256) {
            int j = i >> 6, c = i & 63;
            float v = sp[j * 64 + c] + sp[1024 + j * 64 + c]
                    + sp[2048 + j * 64 + c] + sp[3072 + j * 64 + c];
            atomicAdd(&hT[j * C_ + cg * 64 + c], v);   // fire-and-forget f32
        }
    } else {
        // ---- per-bucket frag counts -> u8 ----
        int bk = bid - 256, cg = bk >> 4, gc = bk & 15;
        for (int i = t; i < 2048; i += 256) h[i] = 0;
        __syncthreads();
        unsigned int count = gcnt_f[bk];
        if (count > RCAP_FRAG) count = RCAP_FRAG;
        const unsigned short* e = entf + (size_t)bk * RCAP_FRAG;
#pragma unroll 4
        for (unsigned int p = t; p < count; p += 256) {
            unsigned int v = e[p];
            unsigned int g_lo = v & 63u;
            unsigned int c_lo = (v >> 6) & 63u;
            atomicAdd(&h[g_lo * 32 + (c_lo >> 1)], 1u << ((c_lo & 1) * 16));
        }
        __syncthreads();
        for (int i = t; i < 1024; i += 256) {
            int g_lo = i >> 4, wb = i & 15;
            unsigned int lo = h[g_lo * 32 + wb * 2];
            unsigned int hi = h[g_lo * 32 + wb * 2 + 1];
            unsigned int outv = (lo & 0xffu) | (((lo >> 16) & 0xffu) << 8)
                              | ((hi & 0xffu) << 16) | (((hi >> 16) & 0xffu) << 24);
            int g = gc * 64 + g_lo;
            if (g < G_)
                fragw[(unsigned)g * 256u + (unsigned)cg * 16u + wb] = outv;
        }
    }
}

// --- 3. latent: BN stats from hT (f64, per block) + sample + KL ------------
__global__ __launch_bounds__(256)
void latent_kernel(const float* __restrict__ hT,     // [16][1024]
                   const float* __restrict__ gamma,
                   const float* __restrict__ beta,
                   const float* __restrict__ W_loc,   // [16][50]
                   const float* __restrict__ b_loc,
                   const float* __restrict__ W_scale, // [16][50]
                   const float* __restrict__ b_scale,
                   const float* __restrict__ eps,     // [1024][50]
                   float* __restrict__ latT,          // [50][1024]
                   __hip_bfloat16* __restrict__ latbf,// [1024][64]
                   double* __restrict__ dacc) {       // [64]
    __shared__ float scs[NHID_], shs[NHID_];
    int t = threadIdx.x;
    {   // phase 1: per-block redundant BN stats (hT is 64 KB, L2-hot)
        int j = t >> 4, cl = t & 15;
        double s1 = 0.0, s2 = 0.0;
#pragma unroll 8
        for (int k = 0; k < 64; ++k) {
            float v = hT[j * C_ + cl + k * 16];
            s1 += (double)v; s2 += (double)v * (double)v;
        }
#pragma unroll
        for (int m = 1; m < 16; m <<= 1) {   // reduce 16-lane groups (same j)
            s1 += __shfl_xor(s1, m);
            s2 += __shfl_xor(s2, m);
        }
        if (cl == 0) {
            double mean = s1 * (1.0 / C_);
            double var = s2 * (1.0 / C_) - mean * mean;
            float rstd = rsqrtf((float)var + 1e-5f);
            float sc = gamma[j] * rstd;
            scs[j] = sc;
            shs[j] = beta[j] - (float)mean * sc;
        }
    }
    __syncthreads();
    int idx = blockIdx.x * 256 + t;
    float kl = 0.f;
    {
        int c = idx / L_;
        int l = idx - c * L_;
        float hb[NHID_];
#pragma unroll
        for (int j = 0; j < NHID_; ++j) {
            float v = fmaf(hT[j * C_ + c], scs[j], shs[j]);
            hb[j] = v > 0.f ? v : 0.f;
        }
        float loc = b_loc[l], ls = b_scale[l];
#pragma unroll
        for (int j = 0; j < NHID_; ++j) {
            loc = fmaf(hb[j], W_loc[j * L_ + l], loc);
            ls  = fmaf(hb[j], W_scale[j * L_ + l], ls);
        }
        float qs = 0.1f * __expf(ls);
        float e = eps[idx];
        float lat = fmaf(qs, e, loc);
        latT[(size_t)l * C_ + c] = lat;
        latbf[c * 64 + l] = __float2bfloat16(lat);
        if (l < 14) latbf[c * 64 + 50 + l] = __float2bfloat16(0.f);  // k-pad
        float z = (lat - loc) / qs;
        kl = fmaf(-0.5f * lat, lat, fmaf(0.5f * z, z, __logf(qs)));
    }
    float s = block_sum_256(kl);
    if (threadIdx.x == 0)
        atomAddF64(&dacc[blockIdx.x & 63], (double)(-CELL_SCALE * s));
}

// --- 4. mixture (swapped-operand MFMA, lane-local softmax) + Poisson -------
// grid (1000, 4): block (g, y) does mixture AND Poisson for cells
// [y*256, y*256+256). D = lwT x latbf^T => lane holds 4 comps of ONE cell.
__global__ __launch_bounds__(256)
void mixpois_kernel(const __hip_bfloat16* __restrict__ latbf, // [1024][64]
                    const __hip_bfloat16* __restrict__ lwT,   // [1000][16][64]
                    const unsigned int* __restrict__ merged,  // [16000][128]
                    const float* __restrict__ baseline,       // [1000][16]
                    const float* __restrict__ latT,           // [50][1024]
                    const float* __restrict__ rw,             // [1000][50]
                    const float* __restrict__ rho_bias,
                    const int* __restrict__ libsize,
                    const unsigned char* __restrict__ fragb,  // [1000][1024]
                    double* __restrict__ dacc,                // [64]
                    unsigned int* __restrict__ done,          // zeroed
                    float* __restrict__ out) {
    int g = blockIdx.x;
    int y = blockIdx.y;
    int t = threadIdx.x;
    int lane = t & 63;
    int wv = t >> 6;
    int s16 = lane & 15;           // A row sel (comp) AND B col sel (cell)
    int quad = lane >> 4;
    const __hip_bfloat16* bb = lwT + (size_t)g * 1024 + s16 * 64 + quad * 8;
    short8 lw1 = *(const short8*)bb;
    short8 lw2 = *(const short8*)(bb + 32);
    const float4 bl4 = *(const float4*)(baseline + g * K_ + quad * 4);
    const unsigned int* mrow =
        merged + (size_t)(g * K_ + quad * 4) * 128u;   // +r*128 per reg
    float partial = 0.f;
    int cwave = y * 256 + wv * 64;
#pragma unroll
    for (int mt = 0; mt < 4; ++mt) {
        int c0 = cwave + mt * 16;
        const __hip_bfloat16* aa = latbf + (size_t)(c0 + s16) * 64 + quad * 8;
        short8 la1 = *(const short8*)aa;
        short8 la2 = *(const short8*)(aa + 32);
        f32x4 d = {bl4.x, bl4.y, bl4.z, bl4.w};
        d = __builtin_amdgcn_mfma_f32_16x16x32_bf16(lw1, la1, d, 0, 0, 0);
        d = __builtin_amdgcn_mfma_f32_16x16x32_bf16(lw2, la2, d, 0, 0, 0);
        float m = fmaxf(fmaxf(d[0], d[1]), fmaxf(d[2], d[3]));
        m = fmaxf(m, __shfl_xor(m, 16));
        m = fmaxf(m, __shfl_xor(m, 32));
        float e0 = __expf(d[0] - m), e1 = __expf(d[1] - m);
        float e2 = __expf(d[2] - m), e3 = __expf(d[3] - m);
        float S = (e0 + e1) + (e2 + e3);
        S += __shfl_xor(S, 16);
        S += __shfl_xor(S, 32);
        float lse = m + __logf(S);
        int cp = c0 + s16;
        unsigned int widx = (unsigned)cp >> 3;
        int sb = (cp & 7) * 4;
#pragma unroll
        for (int r = 0; r < 4; ++r) {
            float cnt = (float)((mrow[r * 128u + widx] >> sb) & 0xfu);
            partial = fmaf(cnt, d[r] - lse, partial);
        }
    }
    // ---- Poisson for the same cell tile ----
    float v;
    {
        int c = y * 256 + t;
        const float* rwg = rw + (size_t)g * L_;   // hoists to SGPRs
        float rho = 0.f;
#pragma unroll 10
        for (int l = 0; l < L_; ++l)
            rho = fmaf(latT[l * C_ + c], rwg[l], rho);
        unsigned int fc = fragb[(size_t)g * C_ + c];
        float fe = rho_bias[g] * __expf(rho) * (float)libsize[c];
        float lf = fmaf((float)fc, __logf(fe), -fe) - LGT[fc > 31u ? 31u : fc];
        v = fmaf(-CUT_SCALE, partial, -CELL_SCALE * lf);
    }
    float contrib = block_sum_256(v);
    // ---- fence-free fused final: atomic f64 accumulate + 2-level counter --
    __shared__ int lastflag;
    if (threadIdx.x == 0) {
        lastflag = 0;
        int slot = blockIdx.x & 63;
        double oldv = atomAddF64(&dacc[slot], (double)contrib);
        unsigned inc = 1u;
        float dep = (float)oldv;
        asm volatile("" : "+v"(inc) : "v"(dep));
        unsigned quota = ((slot < 40) ? 16u : 15u) * 4u;   // 1000 = 15*64+40
        if (atomicAdd(&done[slot * 16], inc) == quota - 1u) {
            if (atomicAdd(&done[1024], 1u) == 63u) lastflag = 1;
        }
    }
    __syncthreads();
    if (lastflag) {
        if (t < 64) {
            double dv = atomAddF64(&dacc[t], 0.0);
#pragma unroll
            for (int m = 1; m < 64; m <<= 1) dv += __shfl_xor(dv, m);
            if (t == 0)
                out[0] = (float)(dv - 138629436.11198905); // -12.5*4e6*log16
        }
    }
}

extern "C" void kernel_launch(void* const* d_in, const int* in_sizes, int n_in,
                              void* d_out, int out_size, void* d_ws, size_t ws_size,
                              hipStream_t stream) {
    const float* cut_coord = (const float*)d_in[0];
    const float* eps       = (const float*)d_in[1];
    const float* enc_W1    = (const float*)d_in[2];
    // d_in[3] = enc_b1 : cancels through BatchNorm, unused
    const float* bn_gamma  = (const float*)d_in[4];
    const float* bn_beta   = (const float*)d_in[5];
    const float* W_loc     = (const float*)d_in[6];
    const float* b_loc     = (const float*)d_in[7];
    const float* W_scale   = (const float*)d_in[8];
    const float* b_scale   = (const float*)d_in[9];
    const float* logit_w   = (const float*)d_in[10];
    const float* rho_w     = (const float*)d_in[11];
    const float* baseline  = (const float*)d_in[12];
    const float* rho_bias  = (const float*)d_in[13];
    const int* cut_cxg     = (const int*)d_in[14];
    const int* frag_ix     = (const int*)d_in[16];
    const int* libsize     = (const int*)d_in[19];

    int n_cuts  = in_sizes[0];
    int n_frags = in_sizes[16];

    char* ws = (char*)d_ws;
    unsigned int*   gcnt_c = (unsigned int*)(ws + GCNTC_OFF);
    unsigned int*   gcnt_f = (unsigned int*)(ws + GCNTF_OFF);
    unsigned int*   done   = (unsigned int*)(ws + DONE_OFF);
    double*         dacc   = (double*)(ws + DACC_OFF);
    float*          hT     = (float*)(ws + HT_OFF);
    __hip_bfloat16* latbf  = (__hip_bfloat16*)(ws + LATBF_OFF);
    __hip_bfloat16* lwT    = (__hip_bfloat16*)(ws + LWT_OFF);
    unsigned short* entc   = (unsigned short*)(ws + ENTC_OFF);
    unsigned short* entf   = (unsigned short*)(ws + ENTF_OFF);
    unsigned int*   merged = (unsigned int*)(ws + MERGED_OFF);
    unsigned int*   fragw  = (unsigned int*)(ws + FRAGU8_OFF);
    float*          latT   = (float*)(ws + LATT_OFF);
    float*          out    = (float*)d_out;

    int ncc = (n_cuts + CHUNK_ - 1) / CHUNK_;
    int ncf = (n_frags + CHUNK_ - 1) / CHUNK_;
    int nblk_part = ncc + ncf;

    hipMemsetAsync(ws, 0, ZERO_BYTES, stream);   // gcnt + done + dacc + hT

    part_kernel<<<nblk_part + 512, 256, 0, stream>>>(
        cut_cxg, cut_coord, frag_ix, gcnt_c, gcnt_f, entc, entf,
        logit_w, rho_w, lwT, dacc,
        n_cuts, n_frags, ncc, nblk_part);
    mid_kernel<<<512, 256, 0, stream>>>(
        gcnt_c, entc, gcnt_f, entf, enc_W1, merged, fragw, hT);
    latent_kernel<<<(C_ * L_) / 256, 256, 0, stream>>>(
        hT, bn_gamma, bn_beta, W_loc, b_loc, W_scale, b_scale,
        eps, latT, latbf, dacc);
    mixpois_kernel<<<dim3(G_, 4), 256, 0, stream>>>(
        latbf, lwT, merged, baseline, latT, rho_w, rho_bias, libsize,
        (const unsigned char*)fragw, dacc, done, out);
}

// Round 6
// 225.288 us; speedup vs baseline: 1.1103x; 1.0854x over previous
//
#include <hip/hip_runtime.h>
#include <hip/hip_bf16.h>
#include <math.h>

// ---------------------------------------------------------------------------
// VAE ELBO (chromatin VAE). Sizes fixed by the reference.
//
//  * NB_ENC == NB_DEC == 16, identical binning => ONE nibble histogram serves
//    both the encoder input (log1p counts) and the mixture likelihood.
//  * r3-r5: global per-record atomics too slow => two-phase LDS counting sort.
//  * r7: same-address atomics serialize ~16ns => per-block partial stores.
//  * r8: roles fused as block-ranges.
//  * r12: hipLaunchCooperativeKernel DOES NOT RUN under this harness.
//  * r13: part = register-staged single pass; mid = hist+enc / frag only.
//  * r14: __threadfence = L2 wb/inv on 8 non-coherent XCD L2s => +138us. BAN.
//  * r15: fence-free tail: f64 atomics into dacc[64]; returning-atomic
//    data-dep orders done-counter. mixpois 179->52.6.
//  * r16: swapped-operand MFMA => lane-local softmax; Poisson fused into
//    mixture blocks, grid (1000,4). mixpois off top-5.
//  * r17: 1024-bucket partition REGRESSED part 41->73 (6-entry runs => 4x
//    write amplification; occupancy 7->5). REVERTED.
//  * r18: full-bucket mid (single-read, 48KB LDS, grid 512) REGRESSED mid
//    42->55: occupancy 11% (2 blocks/CU) on a latency-bound kernel, even
//    though FETCH fell 18->6.4MB. mid is LATENCY-bound: keep >=3 blocks/CU.
//  * r19 (this round): split buckets by CELLS: 2 blocks/bucket, each hists
//    all 1024 bins for its 32-cell half (16KB hist + 16KB w1s = 32KB =>
//    5/CU by LDS, grid 768 => 3/CU). Reads bucket once, discards 1/2 with a
//    1-instr test (r16 discarded 3/4 after full unpack). Reduction scratch
//    overlays dead w1s. part untouched (one variable per round).
// ---------------------------------------------------------------------------

#define G_      1000
#define C_      1024
#define L_      50
#define K_      16
#define NHID_   16
#define CUT_SCALE   12.5f          // N_TOTAL_CUTS / N_CUTS
#define CELL_SCALE  9.765625f      // N_TOTAL_CELLS / N_CELLS

#define CHUNK_    6144
#define RCAP_CUT  18432            // bucket capacity, cuts  (mean 16000)
#define RCAP_FRAG 9216             // bucket capacity, frags (mean 8000)

// ws layout (bytes); [0, ZERO_BYTES) memset per call (gcnt + done + dacc + hT).
#define GCNTC_OFF  0ull
#define GCNTF_OFF  1024ull
#define DONE_OFF   2048ull         // u32: 64 slots @ stride 16 u32, lvl2 @ [1024]
#define DACC_OFF   6400ull         // f64[64] global ELBO accumulator slots
#define HT_OFF     6912ull         // f32 [16][1024] (atomic-accumulated by mid)
#define ZERO_BYTES 72448ull
#define LATBF_OFF  72448ull        // bf16 [1024][64]
#define LWT_OFF    203520ull       // bf16 [1000][16][64]
#define ENTC_OFF   2251520ull      // u16 [256][18432]
#define ENTF_OFF   11688704ull     // u16 [256][9216]
#define MERGED_OFF 16407296ull     // u32 [16000][128] nibble hist
#define FRAGU8_OFF 24599296ull     // u8  [1000][1024]
#define LATT_OFF   25623296ull     // f32 [50][1024]
#define WS_NEED    25828096ull

typedef __attribute__((ext_vector_type(8))) short short8;
typedef __attribute__((ext_vector_type(4))) float f32x4;

__device__ __constant__ float LGT[32] = {   // log(n!)
    0.0f, 0.0f, 0.6931471805599453f, 1.791759469228055f, 3.1780538303479458f,
    4.787491742782046f, 6.579251212010101f, 8.525161361065415f,
    10.60460290274525f, 12.801827480081469f, 15.104412573075516f,
    17.502307845873887f, 19.987214495661885f, 22.552163853123425f,
    25.19122118273868f, 27.89927138384089f, 30.671860106080672f,
    33.50507345013689f, 36.39544520803305f, 39.339884187199495f,
    42.335616460753485f, 45.38013889847691f, 48.47118135183523f,
    51.60667556776438f, 54.78472939811232f, 58.00360522298052f,
    61.261701761002f, 64.55753862700633f, 67.88974313718154f,
    71.25703896716801f, 74.65823634883016f, 78.0922235533153f };

// f64 atomic add at the device coherent point (returns old value; the return
// is used to fabricate ordering dependencies — NO fences anywhere).
__device__ __forceinline__ double atomAddF64(double* p, double v) {
    return __hip_atomic_fetch_add(p, v, __ATOMIC_RELAXED,
                                  __HIP_MEMORY_SCOPE_AGENT);
}

__device__ __forceinline__ float block_sum_256(float v) {
    __shared__ float sm[256];
    int t = threadIdx.x;
    __syncthreads();
    sm[t] = v;
    __syncthreads();
#pragma unroll
    for (int s = 128; s > 0; s >>= 1) {
        if (t < s) sm[t] += sm[t + s];
        __syncthreads();
    }
    return sm[0];
}

// --- 1. part: [0,nblk_part) radix partition (register-staged single pass) |
//        [nblk_part, +256) lwprep | [+256, +512) wkl ------------------------
__global__ __launch_bounds__(256)
void part_kernel(const int* __restrict__ cut_ix,
                 const float* __restrict__ coord,
                 const int* __restrict__ frag_ix,
                 unsigned int* __restrict__ gcnt_c,
                 unsigned int* __restrict__ gcnt_f,
                 unsigned short* __restrict__ entc,
                 unsigned short* __restrict__ entf,
                 const float* __restrict__ lw,      // [1000][50][16]
                 const float* __restrict__ rw,      // [1000][50]
                 __hip_bfloat16* __restrict__ lwT,  // [1000][16][64]
                 double* __restrict__ dacc,         // [64]
                 int n_cuts, int n_frags, int ncc, int nblk_part) {
    int t = threadIdx.x;
    int bid = blockIdx.x;
    if (bid >= nblk_part) {
        int r = bid - nblk_part;
        if (r < 256) {
            // ---- lwprep: bf16 transpose [g][n][64], k-pads zeroed ----
            for (int g = r; g < G_; g += 256) {
                for (int i = t; i < L_ * K_; i += 256) {
                    float v = lw[(size_t)g * (L_ * K_) + i];
                    lwT[(size_t)g * 1024 + (i & 15) * 64 + (i >> 4)] =
                        __float2bfloat16(v);
                }
                for (int i = t; i < 16 * 14; i += 256) {
                    int n = i / 14, l = 50 + (i % 14);
                    lwT[(size_t)g * 1024 + n * 64 + l] = __float2bfloat16(0.f);
                }
            }
        } else {
            // ---- weight KL ----
            const int NTOT = G_ * L_ * K_ + G_ * L_;   // 850000
            int wb = r - 256;
            float s = 0.f;
            for (int i = wb * 256 + t; i < NTOT; i += 256 * 256) {
                float w = (i < G_ * L_ * K_) ? lw[i] : rw[i - G_ * L_ * K_];
                s += fmaf(-50.f * w, w, 1.3836465597893733f);
            }
            s = block_sum_256(s);
            if (t == 0) atomAddF64(&dacc[wb & 63], (double)(-s));
        }
        return;
    }
    // ---- radix partition, one 6144-record chunk per block ----
    __shared__ unsigned int cnt[256], excl[256], cur[256], gbas[256];
    __shared__ unsigned short stage[CHUNK_];
    __shared__ unsigned char bkof[CHUNK_];
    bool isCut = (bid < ncc);
    int blk = isCut ? bid : bid - ncc;
    const int* idx = isCut ? cut_ix : frag_ix;
    int n = isCut ? n_cuts : n_frags;
    int rcap = isCut ? RCAP_CUT : RCAP_FRAG;
    unsigned int* gcount = isCut ? gcnt_c : gcnt_f;
    unsigned short* ent = isCut ? entc : entf;
    int i0 = blk * CHUNK_;
    cnt[t] = 0;
    // stage 24 records in registers: 6 int4 (+6 float4 for cuts), all in flight
    int4 I[6]; float4 X[6];
    unsigned int vm;
    bool full = (i0 + CHUNK_ <= n);
    if (full) {
        const int4* ip = (const int4*)(idx + i0);
#pragma unroll
        for (int k = 0; k < 6; ++k) I[k] = ip[k * 256 + t];
        if (isCut) {
            const float4* xp = (const float4*)(coord + i0);
#pragma unroll
            for (int k = 0; k < 6; ++k) X[k] = xp[k * 256 + t];
        }
        vm = 0xFFFFFFu;
    } else {
        vm = 0;
#pragma unroll
        for (int k = 0; k < 6; ++k) {
            int r0 = i0 + (k * 256 + t) * 4;
            int* Ii = (int*)&I[k]; float* Xi = (float*)&X[k];
#pragma unroll
            for (int u = 0; u < 4; ++u) {
                bool v = (r0 + u) < n;
                if (v) vm |= 1u << (k * 4 + u);
                Ii[u] = v ? idx[r0 + u] : 0;
                Xi[u] = (v && isCut) ? coord[r0 + u] : 0.f;
            }
        }
    }
    __syncthreads();
    // count
#pragma unroll
    for (int k = 0; k < 6; ++k) {
        const int* Ii = (const int*)&I[k];
        const float* Xi = (const float*)&X[k];
#pragma unroll
        for (int u = 0; u < 4; ++u) {
            if (vm & (1u << (k * 4 + u))) {
                int ix = Ii[u];
                int c = ix / G_;
                int g = ix - c * G_;
                unsigned int bk;
                if (isCut) {
                    int b = (int)(Xi[u] * 16.f); b = b > 15 ? 15 : b;
                    bk = ((unsigned)(c >> 6) << 4) | ((unsigned)(g * K_ + b) >> 10);
                } else {
                    bk = ((unsigned)(c >> 6) << 4) | ((unsigned)g >> 6);
                }
                atomicAdd(&cnt[bk], 1u);   // LDS atomic
            }
        }
    }
    __syncthreads();
    // exclusive prefix over 256 bucket counts, single wave, shfl scan
    if (t < 64) {
        unsigned int c0 = cnt[t * 4 + 0], c1 = cnt[t * 4 + 1];
        unsigned int c2 = cnt[t * 4 + 2], c3 = cnt[t * 4 + 3];
        unsigned int tot = c0 + c1 + c2 + c3;
        unsigned int run = tot;
#pragma unroll
        for (int o = 1; o < 64; o <<= 1) {
            unsigned int v = __shfl_up(run, o, 64);
            if (t >= o) run += v;
        }
        unsigned int base = run - tot;          // exclusive over 4-groups
        excl[t * 4 + 0] = base;
        excl[t * 4 + 1] = base + c0;
        excl[t * 4 + 2] = base + c0 + c1;
        excl[t * 4 + 3] = base + c0 + c1 + c2;
    }
    __syncthreads();
    gbas[t] = cnt[t] ? atomicAdd(&gcount[t], cnt[t]) : 0u;  // global reserve
    cur[t] = excl[t];
    __syncthreads();
    // scatter from registers
#pragma unroll
    for (int k = 0; k < 6; ++k) {
        const int* Ii = (const int*)&I[k];
        const float* Xi = (const float*)&X[k];
#pragma unroll
        for (int u = 0; u < 4; ++u) {
            if (vm & (1u << (k * 4 + u))) {
                int ix = Ii[u];
                int c = ix / G_;
                int g = ix - c * G_;
                unsigned int bk; unsigned short e;
                if (isCut) {
                    int b = (int)(Xi[u] * 16.f); b = b > 15 ? 15 : b;
                    int bin = g * K_ + b;
                    bk = ((unsigned)(c >> 6) << 4) | ((unsigned)bin >> 10);
                    e = (unsigned short)(((c & 63) << 10) | (bin & 1023));
                } else {
                    bk = ((unsigned)(c >> 6) << 4) | ((unsigned)g >> 6);
                    e = (unsigned short)(((c & 63) << 6) | (g & 63));
                }
                unsigned int p = atomicAdd(&cur[bk], 1u);   // LDS atomic
                stage[p] = e;
                bkof[p] = (unsigned char)bk;
            }
        }
    }
    __syncthreads();
    int total = n - i0; if (total > CHUNK_) total = CHUNK_;
    for (int p = t; p < total; p += 256) {
        unsigned int bk = bkof[p];
        unsigned int dst = gbas[bk] + (p - excl[bk]);
        if (dst < (unsigned)rcap)
            ent[(size_t)bk * rcap + dst] = stage[p];
    }
}

// --- 2. mid kernel: [0,512) half-cell bucket hist+enc | [512,768) frag -----
// r19: 2 blocks per bucket, split by CELLS (32 each). Each block reads the
// bucket once, discards 1/2 with a 1-instr test, hists all 1024 bins for its
// cell-half in 16KB. LDS 32KB (5/CU); grid 768 (3/CU).
__global__ __launch_bounds__(256)
void mid_kernel(const unsigned int* __restrict__ gcnt_c,
                const unsigned short* __restrict__ entc,
                const unsigned int* __restrict__ gcnt_f,
                const unsigned short* __restrict__ entf,
                const float* __restrict__ W1,        // [16000][16]
                unsigned int* __restrict__ merged,   // [16000][128]
                unsigned int* __restrict__ fragw,    // u8[1000][1024] as u32
                float* __restrict__ hT) {            // [16][1024], pre-zeroed
    __shared__ unsigned int h[4096];   // 16 KB: [1024 bins][32 cells] nibbles
    __shared__ float w1s[4096];        // 16 KB W1 chunk stage / reduction sp
    int t = threadIdx.x;
    int bid = blockIdx.x;
    if (bid < 512) {
        // ---- half-cell bucket: 1024 bins x 32 cells ----
        int bk = bid >> 1, half = bid & 1;
        int cg = bk >> 4, bc = bk & 15;
        for (int i = t; i < 4096; i += 256) h[i] = 0;
        __syncthreads();
        unsigned int count = gcnt_c[bk];
        if (count > RCAP_CUT) count = RCAP_CUT;
        const unsigned int* e32 = (const unsigned int*)(entc + (size_t)bk * RCAP_CUT);
        unsigned int hsel = (unsigned)half << 5;
        unsigned int npair = count >> 1;
        for (unsigned int base = 0; base < npair; base += 1024) {
            unsigned int w[4]; bool val[4];
#pragma unroll
            for (int u = 0; u < 4; ++u) {
                unsigned int p = base + u * 256 + t;
                val[u] = (p < npair);
                w[u] = val[u] ? e32[p] : 0u;
            }
#pragma unroll
            for (int u = 0; u < 4; ++u) {
                if (val[u]) {
                    unsigned int v0 = w[u] & 0xffffu, v1 = w[u] >> 16;
                    unsigned int c0 = v0 >> 10, c1 = v1 >> 10;
                    if ((c0 & 32u) == hsel) {
                        unsigned int cc = c0 & 31u;
                        atomicAdd(&h[(v0 & 1023u) * 4 + (cc >> 3)],
                                  1u << ((cc & 7) * 4));
                    }
                    if ((c1 & 32u) == hsel) {
                        unsigned int cc = c1 & 31u;
                        atomicAdd(&h[(v1 & 1023u) * 4 + (cc >> 3)],
                                  1u << ((cc & 7) * 4));
                    }
                }
            }
        }
        if (t == 0 && (count & 1u)) {
            unsigned int v = ((const unsigned short*)e32)[count - 1];
            unsigned int c0 = v >> 10;
            if ((c0 & 32u) == hsel) {
                unsigned int cc = c0 & 31u;
                atomicAdd(&h[(v & 1023u) * 4 + (cc >> 3)], 1u << ((cc & 7) * 4));
            }
        }
        __syncthreads();
        // merged: this block owns words [cg*8 + half*4 .. +4) of each bin row
        for (int i = t; i < 4096; i += 256) {
            int binlo = i >> 2, wq = i & 3;
            int bin = bc * 1024 + binlo;
            if (bin < 16000)
                merged[(unsigned)bin * 128u + (unsigned)(cg * 8 + half * 4 + wq)]
                    = h[i];
        }
        // ---- encoder: 1024 rows x 32 cells, 4 chunks of 256 rows ----
        int c32 = t & 31, sub = t >> 5;     // 8 subwave groups
        int sh = (c32 & 7) * 4, widx = c32 >> 3;
        float acc[NHID_];
#pragma unroll
        for (int j = 0; j < NHID_; ++j) acc[j] = 0.f;
        for (int q = 0; q < 4; ++q) {
            __syncthreads();               // prev chunk's w1s reads done
            int wbase = (bc * 1024 + q * 256) * NHID_;
#pragma unroll
            for (int r = 0; r < 16; ++r) {
                int i = r * 256 + t;
                int gi = wbase + i;
                w1s[i] = (gi < 16000 * NHID_) ? W1[gi] : 0.f;
            }
            __syncthreads();
            const float4* w1v = (const float4*)w1s;
            int rl0 = q * 256 + sub * 32;
            // rows >= 16000: h==0 => xv=log(1)=0 and w1s staged 0 => no-op,
            // so no guard needed.
#pragma unroll 4
            for (int bl = 0; bl < 32; ++bl) {
                int rl = rl0 + bl;           // hist row 0..1023
                int rwc = sub * 32 + bl;     // w1s row 0..255
                unsigned int w = h[rl * 4 + widx];
                float xv = __logf((float)(((w >> sh) & 0xfu) + 1u));
                float4 wa = w1v[rwc * 4 + 0];
                float4 wb = w1v[rwc * 4 + 1];
                float4 wc = w1v[rwc * 4 + 2];
                float4 wd = w1v[rwc * 4 + 3];
                acc[0] = fmaf(xv, wa.x, acc[0]);  acc[1] = fmaf(xv, wa.y, acc[1]);
                acc[2] = fmaf(xv, wa.z, acc[2]);  acc[3] = fmaf(xv, wa.w, acc[3]);
                acc[4] = fmaf(xv, wb.x, acc[4]);  acc[5] = fmaf(xv, wb.y, acc[5]);
                acc[6] = fmaf(xv, wb.z, acc[6]);  acc[7] = fmaf(xv, wb.w, acc[7]);
                acc[8] = fmaf(xv, wc.x, acc[8]);  acc[9] = fmaf(xv, wc.y, acc[9]);
                acc[10] = fmaf(xv, wc.z, acc[10]); acc[11] = fmaf(xv, wc.w, acc[11]);
                acc[12] = fmaf(xv, wd.x, acc[12]); acc[13] = fmaf(xv, wd.y, acc[13]);
                acc[14] = fmaf(xv, wd.z, acc[14]); acc[15] = fmaf(xv, wd.w, acc[15]);
            }
        }
        __syncthreads();               // w1s dead; reuse as reduction sp
        float* sp = (float*)w1s;       // [8 subs][16 j][32 c] = 4096 floats
#pragma unroll
        for (int j = 0; j < NHID_; ++j) sp[sub * 512 + j * 32 + c32] = acc[j];
        __syncthreads();
        for (int i = t; i < 512; i += 256) {
            int j = i >> 5, cc = i & 31;
            float v = 0.f;
#pragma unroll
            for (int s = 0; s < 8; ++s) v += sp[s * 512 + j * 32 + cc];
            atomicAdd(&hT[j * C_ + cg * 64 + half * 32 + cc], v);
        }
    } else {
        // ---- per-bucket frag counts -> u8 ----
        int bk = bid - 512, cg = bk >> 4, gc = bk & 15;
        for (int i = t; i < 2048; i += 256) h[i] = 0;
        __syncthreads();
        unsigned int count = gcnt_f[bk];
        if (count > RCAP_FRAG) count = RCAP_FRAG;
        const unsigned short* e = entf + (size_t)bk * RCAP_FRAG;
#pragma unroll 4
        for (unsigned int p = t; p < count; p += 256) {
            unsigned int v = e[p];
            unsigned int g_lo = v & 63u;
            unsigned int c_lo = (v >> 6) & 63u;
            atomicAdd(&h[g_lo * 32 + (c_lo >> 1)], 1u << ((c_lo & 1) * 16));
        }
        __syncthreads();
        for (int i = t; i < 1024; i += 256) {
            int g_lo = i >> 4, wb = i & 15;
            unsigned int lo = h[g_lo * 32 + wb * 2];
            unsigned int hi = h[g_lo * 32 + wb * 2 + 1];
            unsigned int outv = (lo & 0xffu) | (((lo >> 16) & 0xffu) << 8)
                              | ((hi & 0xffu) << 16) | (((hi >> 16) & 0xffu) << 24);
            int g = gc * 64 + g_lo;
            if (g < G_)
                fragw[(unsigned)g * 256u + (unsigned)cg * 16u + wb] = outv;
        }
    }
}

// --- 3. latent: BN stats from hT (f64, per block) + sample + KL ------------
__global__ __launch_bounds__(256)
void latent_kernel(const float* __restrict__ hT,     // [16][1024]
                   const float* __restrict__ gamma,
                   const float* __restrict__ beta,
                   const float* __restrict__ W_loc,   // [16][50]
                   const float* __restrict__ b_loc,
                   const float* __restrict__ W_scale, // [16][50]
                   const float* __restrict__ b_scale,
                   const float* __restrict__ eps,     // [1024][50]
                   float* __restrict__ latT,          // [50][1024]
                   __hip_bfloat16* __restrict__ latbf,// [1024][64]
                   double* __restrict__ dacc) {       // [64]
    __shared__ float scs[NHID_], shs[NHID_];
    int t = threadIdx.x;
    {   // phase 1: per-block redundant BN stats (hT is 64 KB, L2-hot)
        int j = t >> 4, cl = t & 15;
        double s1 = 0.0, s2 = 0.0;
#pragma unroll 8
        for (int k = 0; k < 64; ++k) {
            float v = hT[j * C_ + cl + k * 16];
            s1 += (double)v; s2 += (double)v * (double)v;
        }
#pragma unroll
        for (int m = 1; m < 16; m <<= 1) {   // reduce 16-lane groups (same j)
            s1 += __shfl_xor(s1, m);
            s2 += __shfl_xor(s2, m);
        }
        if (cl == 0) {
            double mean = s1 * (1.0 / C_);
            double var = s2 * (1.0 / C_) - mean * mean;
            float rstd = rsqrtf((float)var + 1e-5f);
            float sc = gamma[j] * rstd;
            scs[j] = sc;
            shs[j] = beta[j] - (float)mean * sc;
        }
    }
    __syncthreads();
    int idx = blockIdx.x * 256 + t;
    float kl = 0.f;
    {
        int c = idx / L_;
        int l = idx - c * L_;
        float hb[NHID_];
#pragma unroll
        for (int j = 0; j < NHID_; ++j) {
            float v = fmaf(hT[j * C_ + c], scs[j], shs[j]);
            hb[j] = v > 0.f ? v : 0.f;
        }
        float loc = b_loc[l], ls = b_scale[l];
#pragma unroll
        for (int j = 0; j < NHID_; ++j) {
            loc = fmaf(hb[j], W_loc[j * L_ + l], loc);
            ls  = fmaf(hb[j], W_scale[j * L_ + l], ls);
        }
        float qs = 0.1f * __expf(ls);
        float e = eps[idx];
        float lat = fmaf(qs, e, loc);
        latT[(size_t)l * C_ + c] = lat;
        latbf[c * 64 + l] = __float2bfloat16(lat);
        if (l < 14) latbf[c * 64 + 50 + l] = __float2bfloat16(0.f);  // k-pad
        float z = (lat - loc) / qs;
        kl = fmaf(-0.5f * lat, lat, fmaf(0.5f * z, z, __logf(qs)));
    }
    float s = block_sum_256(kl);
    if (threadIdx.x == 0)
        atomAddF64(&dacc[blockIdx.x & 63], (double)(-CELL_SCALE * s));
}

// --- 4. mixture (swapped-operand MFMA, lane-local softmax) + Poisson -------
// grid (1000, 4): block (g, y) does mixture AND Poisson for cells
// [y*256, y*256+256). D = lwT x latbf^T => lane holds 4 comps of ONE cell.
__global__ __launch_bounds__(256)
void mixpois_kernel(const __hip_bfloat16* __restrict__ latbf, // [1024][64]
                    const __hip_bfloat16* __restrict__ lwT,   // [1000][16][64]
                    const unsigned int* __restrict__ merged,  // [16000][128]
                    const float* __restrict__ baseline,       // [1000][16]
                    const float* __restrict__ latT,           // [50][1024]
                    const float* __restrict__ rw,             // [1000][50]
                    const float* __restrict__ rho_bias,
                    const int* __restrict__ libsize,
                    const unsigned char* __restrict__ fragb,  // [1000][1024]
                    double* __restrict__ dacc,                // [64]
                    unsigned int* __restrict__ done,          // zeroed
                    float* __restrict__ out) {
    int g = blockIdx.x;
    int y = blockIdx.y;
    int t = threadIdx.x;
    int lane = t & 63;
    int wv = t >> 6;
    int s16 = lane & 15;           // A row sel (comp) AND B col sel (cell)
    int quad = lane >> 4;
    const __hip_bfloat16* bb = lwT + (size_t)g * 1024 + s16 * 64 + quad * 8;
    short8 lw1 = *(const short8*)bb;
    short8 lw2 = *(const short8*)(bb + 32);
    const float4 bl4 = *(const float4*)(baseline + g * K_ + quad * 4);
    const unsigned int* mrow =
        merged + (size_t)(g * K_ + quad * 4) * 128u;   // +r*128 per reg
    float partial = 0.f;
    int cwave = y * 256 + wv * 64;
#pragma unroll
    for (int mt = 0; mt < 4; ++mt) {
        int c0 = cwave + mt * 16;
        const __hip_bfloat16* aa = latbf + (size_t)(c0 + s16) * 64 + quad * 8;
        short8 la1 = *(const short8*)aa;
        short8 la2 = *(const short8*)(aa + 32);
        f32x4 d = {bl4.x, bl4.y, bl4.z, bl4.w};
        d = __builtin_amdgcn_mfma_f32_16x16x32_bf16(lw1, la1, d, 0, 0, 0);
        d = __builtin_amdgcn_mfma_f32_16x16x32_bf16(lw2, la2, d, 0, 0, 0);
        float m = fmaxf(fmaxf(d[0], d[1]), fmaxf(d[2], d[3]));
        m = fmaxf(m, __shfl_xor(m, 16));
        m = fmaxf(m, __shfl_xor(m, 32));
        float e0 = __expf(d[0] - m), e1 = __expf(d[1] - m);
        float e2 = __expf(d[2] - m), e3 = __expf(d[3] - m);
        float S = (e0 + e1) + (e2 + e3);
        S += __shfl_xor(S, 16);
        S += __shfl_xor(S, 32);
        float lse = m + __logf(S);
        int cp = c0 + s16;
        unsigned int widx = (unsigned)cp >> 3;
        int sb = (cp & 7) * 4;
#pragma unroll
        for (int r = 0; r < 4; ++r) {
            float cnt = (float)((mrow[r * 128u + widx] >> sb) & 0xfu);
            partial = fmaf(cnt, d[r] - lse, partial);
        }
    }
    // ---- Poisson for the same cell tile ----
    float v;
    {
        int c = y * 256 + t;
        const float* rwg = rw + (size_t)g * L_;   // hoists to SGPRs
        float rho = 0.f;
#pragma unroll 10
        for (int l = 0; l < L_; ++l)
            rho = fmaf(latT[l * C_ + c], rwg[l], rho);
        unsigned int fc = fragb[(size_t)g * C_ + c];
        float fe = rho_bias[g] * __expf(rho) * (float)libsize[c];
        float lf = fmaf((float)fc, __logf(fe), -fe) - LGT[fc > 31u ? 31u : fc];
        v = fmaf(-CUT_SCALE, partial, -CELL_SCALE * lf);
    }
    float contrib = block_sum_256(v);
    // ---- fence-free fused final: atomic f64 accumulate + 2-level counter --
    __shared__ int lastflag;
    if (threadIdx.x == 0) {
        lastflag = 0;
        int slot = blockIdx.x & 63;
        double oldv = atomAddF64(&dacc[slot], (double)contrib);
        unsigned inc = 1u;
        float dep = (float)oldv;
        asm volatile("" : "+v"(inc) : "v"(dep));
        unsigned quota = ((slot < 40) ? 16u : 15u) * 4u;   // 1000 = 15*64+40
        if (atomicAdd(&done[slot * 16], inc) == quota - 1u) {
            if (atomicAdd(&done[1024], 1u) == 63u) lastflag = 1;
        }
    }
    __syncthreads();
    if (lastflag) {
        if (t < 64) {
            double dv = atomAddF64(&dacc[t], 0.0);
#pragma unroll
            for (int m = 1; m < 64; m <<= 1) dv += __shfl_xor(dv, m);
            if (t == 0)
                out[0] = (float)(dv - 138629436.11198905); // -12.5*4e6*log16
        }
    }
}

extern "C" void kernel_launch(void* const* d_in, const int* in_sizes, int n_in,
                              void* d_out, int out_size, void* d_ws, size_t ws_size,
                              hipStream_t stream) {
    const float* cut_coord = (const float*)d_in[0];
    const float* eps       = (const float*)d_in[1];
    const float* enc_W1    = (const float*)d_in[2];
    // d_in[3] = enc_b1 : cancels through BatchNorm, unused
    const float* bn_gamma  = (const float*)d_in[4];
    const float* bn_beta   = (const float*)d_in[5];
    const float* W_loc     = (const float*)d_in[6];
    const float* b_loc     = (const float*)d_in[7];
    const float* W_scale   = (const float*)d_in[8];
    const float* b_scale   = (const float*)d_in[9];
    const float* logit_w   = (const float*)d_in[10];
    const float* rho_w     = (const float*)d_in[11];
    const float* baseline  = (const float*)d_in[12];
    const float* rho_bias  = (const float*)d_in[13];
    const int* cut_cxg     = (const int*)d_in[14];
    const int* frag_ix     = (const int*)d_in[16];
    const int* libsize     = (const int*)d_in[19];

    int n_cuts  = in_sizes[0];
    int n_frags = in_sizes[16];

    char* ws = (char*)d_ws;
    unsigned int*   gcnt_c = (unsigned int*)(ws + GCNTC_OFF);
    unsigned int*   gcnt_f = (unsigned int*)(ws + GCNTF_OFF);
    unsigned int*   done   = (unsigned int*)(ws + DONE_OFF);
    double*         dacc   = (double*)(ws + DACC_OFF);
    float*          hT     = (float*)(ws + HT_OFF);
    __hip_bfloat16* latbf  = (__hip_bfloat16*)(ws + LATBF_OFF);
    __hip_bfloat16* lwT    = (__hip_bfloat16*)(ws + LWT_OFF);
    unsigned short* entc   = (unsigned short*)(ws + ENTC_OFF);
    unsigned short* entf   = (unsigned short*)(ws + ENTF_OFF);
    unsigned int*   merged = (unsigned int*)(ws + MERGED_OFF);
    unsigned int*   fragw  = (unsigned int*)(ws + FRAGU8_OFF);
    float*          latT   = (float*)(ws + LATT_OFF);
    float*          out    = (float*)d_out;

    int ncc = (n_cuts + CHUNK_ - 1) / CHUNK_;
    int ncf = (n_frags + CHUNK_ - 1) / CHUNK_;
    int nblk_part = ncc + ncf;

    hipMemsetAsync(ws, 0, ZERO_BYTES, stream);   // gcnt + done + dacc + hT

    part_kernel<<<nblk_part + 512, 256, 0, stream>>>(
        cut_cxg, cut_coord, frag_ix, gcnt_c, gcnt_f, entc, entf,
        logit_w, rho_w, lwT, dacc,
        n_cuts, n_frags, ncc, nblk_part);
    mid_kernel<<<768, 256, 0, stream>>>(
        gcnt_c, entc, gcnt_f, entf, enc_W1, merged, fragw, hT);
    latent_kernel<<<(C_ * L_) / 256, 256, 0, stream>>>(
        hT, bn_gamma, bn_beta, W_loc, b_loc, W_scale, b_scale,
        eps, latT, latbf, dacc);
    mixpois_kernel<<<dim3(G_, 4), 256, 0, stream>>>(
        latbf, lwT, merged, baseline, latT, rho_w, rho_bias, libsize,
        (const unsigned char*)fragw, dacc, done, out);
}

// Round 7
// 220.653 us; speedup vs baseline: 1.1336x; 1.0210x over previous
//
#include <hip/hip_runtime.h>
#include <hip/hip_bf16.h>
#include <math.h>

// ---------------------------------------------------------------------------
// VAE ELBO (chromatin VAE). Sizes fixed by the reference.
//
//  * NB_ENC == NB_DEC == 16, identical binning => ONE nibble histogram serves
//    both the encoder input (log1p counts) and the mixture likelihood.
//  * r3-r5: global per-record atomics too slow => two-phase LDS counting sort.
//  * r7: same-address atomics serialize ~16ns => per-block partial stores.
//  * r8: roles fused as block-ranges.
//  * r12: hipLaunchCooperativeKernel DOES NOT RUN under this harness.
//  * r13: part = register-staged single pass; mid = hist+enc / frag only.
//  * r14: __threadfence = L2 wb/inv on 8 non-coherent XCD L2s => +138us. BAN.
//  * r15: fence-free tail: f64 atomics into dacc[64]; returning-atomic
//    data-dep orders done-counter. mixpois 179->52.6.
//  * r16: swapped-operand MFMA => lane-local softmax; Poisson fused in.
//  * r17: 1024-bucket partition REGRESSED part 41->73 (write amp). REVERTED.
//  * r18: 48KB-LDS mid REGRESSED (2 blocks/CU, latency-bound). REVERTED.
//  * r19: mid split by CELLS (2 blocks/bucket, 32KB LDS, grid 768): WIN,
//    mid off top-5. All kernels now <40.5us.
//  * r20 (this round): part was LDS-atomic-pipe bound (2 atomics/record,
//    12M total + dependent scatter chain + bucket math twice). FIX: count
//    atomic RETURNS the intra-bucket rank; scatter = stage[excl[bk]+rank],
//    no atomic, (e,bk,rank) cached in dead I/X registers. mixpois: per-block
//    fixed costs dominate (VALU floor ~4us) => grid (1000,4)->(1000,2),
//    512 cells/block (8 tiles/wave, 2 Poisson cells/thread).
// ---------------------------------------------------------------------------

#define G_      1000
#define C_      1024
#define L_      50
#define K_      16
#define NHID_   16
#define CUT_SCALE   12.5f          // N_TOTAL_CUTS / N_CUTS
#define CELL_SCALE  9.765625f      // N_TOTAL_CELLS / N_CELLS

#define CHUNK_    6144
#define RCAP_CUT  18432            // bucket capacity, cuts  (mean 16000)
#define RCAP_FRAG 9216             // bucket capacity, frags (mean 8000)

// ws layout (bytes); [0, ZERO_BYTES) memset per call (gcnt + done + dacc + hT).
#define GCNTC_OFF  0ull
#define GCNTF_OFF  1024ull
#define DONE_OFF   2048ull         // u32: 64 slots @ stride 16 u32, lvl2 @ [1024]
#define DACC_OFF   6400ull         // f64[64] global ELBO accumulator slots
#define HT_OFF     6912ull         // f32 [16][1024] (atomic-accumulated by mid)
#define ZERO_BYTES 72448ull
#define LATBF_OFF  72448ull        // bf16 [1024][64]
#define LWT_OFF    203520ull       // bf16 [1000][16][64]
#define ENTC_OFF   2251520ull      // u16 [256][18432]
#define ENTF_OFF   11688704ull     // u16 [256][9216]
#define MERGED_OFF 16407296ull     // u32 [16000][128] nibble hist
#define FRAGU8_OFF 24599296ull     // u8  [1000][1024]
#define LATT_OFF   25623296ull     // f32 [50][1024]
#define WS_NEED    25828096ull

typedef __attribute__((ext_vector_type(8))) short short8;
typedef __attribute__((ext_vector_type(4))) float f32x4;

__device__ __constant__ float LGT[32] = {   // log(n!)
    0.0f, 0.0f, 0.6931471805599453f, 1.791759469228055f, 3.1780538303479458f,
    4.787491742782046f, 6.579251212010101f, 8.525161361065415f,
    10.60460290274525f, 12.801827480081469f, 15.104412573075516f,
    17.502307845873887f, 19.987214495661885f, 22.552163853123425f,
    25.19122118273868f, 27.89927138384089f, 30.671860106080672f,
    33.50507345013689f, 36.39544520803305f, 39.339884187199495f,
    42.335616460753485f, 45.38013889847691f, 48.47118135183523f,
    51.60667556776438f, 54.78472939811232f, 58.00360522298052f,
    61.261701761002f, 64.55753862700633f, 67.88974313718154f,
    71.25703896716801f, 74.65823634883016f, 78.0922235533153f };

// f64 atomic add at the device coherent point (returns old value; the return
// is used to fabricate ordering dependencies — NO fences anywhere).
__device__ __forceinline__ double atomAddF64(double* p, double v) {
    return __hip_atomic_fetch_add(p, v, __ATOMIC_RELAXED,
                                  __HIP_MEMORY_SCOPE_AGENT);
}

__device__ __forceinline__ float block_sum_256(float v) {
    __shared__ float sm[256];
    int t = threadIdx.x;
    __syncthreads();
    sm[t] = v;
    __syncthreads();
#pragma unroll
    for (int s = 128; s > 0; s >>= 1) {
        if (t < s) sm[t] += sm[t + s];
        __syncthreads();
    }
    return sm[0];
}

// --- 1. part: [0,nblk_part) radix partition (rank-from-count, no scatter
//        atomics) | [nblk_part, +256) lwprep | [+256, +512) wkl -------------
__global__ __launch_bounds__(256)
void part_kernel(const int* __restrict__ cut_ix,
                 const float* __restrict__ coord,
                 const int* __restrict__ frag_ix,
                 unsigned int* __restrict__ gcnt_c,
                 unsigned int* __restrict__ gcnt_f,
                 unsigned short* __restrict__ entc,
                 unsigned short* __restrict__ entf,
                 const float* __restrict__ lw,      // [1000][50][16]
                 const float* __restrict__ rw,      // [1000][50]
                 __hip_bfloat16* __restrict__ lwT,  // [1000][16][64]
                 double* __restrict__ dacc,         // [64]
                 int n_cuts, int n_frags, int ncc, int nblk_part) {
    int t = threadIdx.x;
    int bid = blockIdx.x;
    if (bid >= nblk_part) {
        int r = bid - nblk_part;
        if (r < 256) {
            // ---- lwprep: bf16 transpose [g][n][64], k-pads zeroed ----
            for (int g = r; g < G_; g += 256) {
                for (int i = t; i < L_ * K_; i += 256) {
                    float v = lw[(size_t)g * (L_ * K_) + i];
                    lwT[(size_t)g * 1024 + (i & 15) * 64 + (i >> 4)] =
                        __float2bfloat16(v);
                }
                for (int i = t; i < 16 * 14; i += 256) {
                    int n = i / 14, l = 50 + (i % 14);
                    lwT[(size_t)g * 1024 + n * 64 + l] = __float2bfloat16(0.f);
                }
            }
        } else {
            // ---- weight KL ----
            const int NTOT = G_ * L_ * K_ + G_ * L_;   // 850000
            int wb = r - 256;
            float s = 0.f;
            for (int i = wb * 256 + t; i < NTOT; i += 256 * 256) {
                float w = (i < G_ * L_ * K_) ? lw[i] : rw[i - G_ * L_ * K_];
                s += fmaf(-50.f * w, w, 1.3836465597893733f);
            }
            s = block_sum_256(s);
            if (t == 0) atomAddF64(&dacc[wb & 63], (double)(-s));
        }
        return;
    }
    // ---- radix partition, one 6144-record chunk per block ----
    __shared__ unsigned int cnt[256], excl[256], gbas[256];
    __shared__ unsigned short stage[CHUNK_];
    __shared__ unsigned char bkof[CHUNK_];
    bool isCut = (bid < ncc);
    int blk = isCut ? bid : bid - ncc;
    const int* idx = isCut ? cut_ix : frag_ix;
    int n = isCut ? n_cuts : n_frags;
    int rcap = isCut ? RCAP_CUT : RCAP_FRAG;
    unsigned int* gcount = isCut ? gcnt_c : gcnt_f;
    unsigned short* ent = isCut ? entc : entf;
    int i0 = blk * CHUNK_;
    cnt[t] = 0;
    // stage 24 records in registers: 6 int4 (+6 float4 for cuts), all in flight
    int4 I[6]; float4 X[6];
    unsigned int vm;
    bool full = (i0 + CHUNK_ <= n);
    if (full) {
        const int4* ip = (const int4*)(idx + i0);
#pragma unroll
        for (int k = 0; k < 6; ++k) I[k] = ip[k * 256 + t];
        if (isCut) {
            const float4* xp = (const float4*)(coord + i0);
#pragma unroll
            for (int k = 0; k < 6; ++k) X[k] = xp[k * 256 + t];
        }
        vm = 0xFFFFFFu;
    } else {
        vm = 0;
#pragma unroll
        for (int k = 0; k < 6; ++k) {
            int r0 = i0 + (k * 256 + t) * 4;
            int* Ii = (int*)&I[k]; float* Xi = (float*)&X[k];
#pragma unroll
            for (int u = 0; u < 4; ++u) {
                bool v = (r0 + u) < n;
                if (v) vm |= 1u << (k * 4 + u);
                Ii[u] = v ? idx[r0 + u] : 0;
                Xi[u] = (v && isCut) ? coord[r0 + u] : 0.f;
            }
        }
    }
    __syncthreads();
    // count phase: compute (e,bk) ONCE, rank = returning atomic; cache all
    // three in the now-dead I/X registers (r20).
#pragma unroll
    for (int k = 0; k < 6; ++k) {
        int* Ii = (int*)&I[k];
        unsigned int* Xi = (unsigned int*)&X[k];
#pragma unroll
        for (int u = 0; u < 4; ++u) {
            if (vm & (1u << (k * 4 + u))) {
                int ix = Ii[u];
                int c = ix / G_;
                int g = ix - c * G_;
                unsigned int bk; unsigned int e;
                if (isCut) {
                    float xf = ((const float*)Xi)[u];
                    int b = (int)(xf * 16.f); b = b > 15 ? 15 : b;
                    int bin = g * K_ + b;
                    bk = ((unsigned)(c >> 6) << 4) | ((unsigned)bin >> 10);
                    e = ((unsigned)(c & 63) << 10) | ((unsigned)bin & 1023u);
                } else {
                    bk = ((unsigned)(c >> 6) << 4) | ((unsigned)g >> 6);
                    e = ((unsigned)(c & 63) << 6) | ((unsigned)g & 63u);
                }
                unsigned int rank = atomicAdd(&cnt[bk], 1u);  // LDS, returning
                Ii[u] = (int)(e | (bk << 16));
                Xi[u] = rank;
            }
        }
    }
    __syncthreads();
    // exclusive prefix over 256 bucket counts, single wave, shfl scan
    if (t < 64) {
        unsigned int c0 = cnt[t * 4 + 0], c1 = cnt[t * 4 + 1];
        unsigned int c2 = cnt[t * 4 + 2], c3 = cnt[t * 4 + 3];
        unsigned int tot = c0 + c1 + c2 + c3;
        unsigned int run = tot;
#pragma unroll
        for (int o = 1; o < 64; o <<= 1) {
            unsigned int v = __shfl_up(run, o, 64);
            if (t >= o) run += v;
        }
        unsigned int base = run - tot;          // exclusive over 4-groups
        excl[t * 4 + 0] = base;
        excl[t * 4 + 1] = base + c0;
        excl[t * 4 + 2] = base + c0 + c1;
        excl[t * 4 + 3] = base + c0 + c1 + c2;
    }
    __syncthreads();
    gbas[t] = cnt[t] ? atomicAdd(&gcount[t], cnt[t]) : 0u;  // global reserve
    // scatter from registers: p = excl[bk] + rank — NO atomics (r20)
#pragma unroll
    for (int k = 0; k < 6; ++k) {
        const unsigned int* Ii = (const unsigned int*)&I[k];
        const unsigned int* Xi = (const unsigned int*)&X[k];
#pragma unroll
        for (int u = 0; u < 4; ++u) {
            if (vm & (1u << (k * 4 + u))) {
                unsigned int w = Ii[u];
                unsigned int bk = w >> 16;
                unsigned int p = excl[bk] + Xi[u];
                stage[p] = (unsigned short)(w & 0xffffu);
                bkof[p] = (unsigned char)bk;
            }
        }
    }
    __syncthreads();
    int total = n - i0; if (total > CHUNK_) total = CHUNK_;
    for (int p = t; p < total; p += 256) {
        unsigned int bk = bkof[p];
        unsigned int dst = gbas[bk] + (p - excl[bk]);
        if (dst < (unsigned)rcap)
            ent[(size_t)bk * rcap + dst] = stage[p];
    }
}

// --- 2. mid kernel: [0,512) half-cell bucket hist+enc | [512,768) frag -----
// r19: 2 blocks per bucket, split by CELLS (32 each). Each block reads the
// bucket once, discards 1/2 with a 1-instr test, hists all 1024 bins for its
// cell-half in 16KB. LDS 32KB (5/CU); grid 768 (3/CU).
__global__ __launch_bounds__(256)
void mid_kernel(const unsigned int* __restrict__ gcnt_c,
                const unsigned short* __restrict__ entc,
                const unsigned int* __restrict__ gcnt_f,
                const unsigned short* __restrict__ entf,
                const float* __restrict__ W1,        // [16000][16]
                unsigned int* __restrict__ merged,   // [16000][128]
                unsigned int* __restrict__ fragw,    // u8[1000][1024] as u32
                float* __restrict__ hT) {            // [16][1024], pre-zeroed
    __shared__ unsigned int h[4096];   // 16 KB: [1024 bins][32 cells] nibbles
    __shared__ float w1s[4096];        // 16 KB W1 chunk stage / reduction sp
    int t = threadIdx.x;
    int bid = blockIdx.x;
    if (bid < 512) {
        // ---- half-cell bucket: 1024 bins x 32 cells ----
        int bk = bid >> 1, half = bid & 1;
        int cg = bk >> 4, bc = bk & 15;
        for (int i = t; i < 4096; i += 256) h[i] = 0;
        __syncthreads();
        unsigned int count = gcnt_c[bk];
        if (count > RCAP_CUT) count = RCAP_CUT;
        const unsigned int* e32 = (const unsigned int*)(entc + (size_t)bk * RCAP_CUT);
        unsigned int hsel = (unsigned)half << 5;
        unsigned int npair = count >> 1;
        for (unsigned int base = 0; base < npair; base += 1024) {
            unsigned int w[4]; bool val[4];
#pragma unroll
            for (int u = 0; u < 4; ++u) {
                unsigned int p = base + u * 256 + t;
                val[u] = (p < npair);
                w[u] = val[u] ? e32[p] : 0u;
            }
#pragma unroll
            for (int u = 0; u < 4; ++u) {
                if (val[u]) {
                    unsigned int v0 = w[u] & 0xffffu, v1 = w[u] >> 16;
                    unsigned int c0 = v0 >> 10, c1 = v1 >> 10;
                    if ((c0 & 32u) == hsel) {
                        unsigned int cc = c0 & 31u;
                        atomicAdd(&h[(v0 & 1023u) * 4 + (cc >> 3)],
                                  1u << ((cc & 7) * 4));
                    }
                    if ((c1 & 32u) == hsel) {
                        unsigned int cc = c1 & 31u;
                        atomicAdd(&h[(v1 & 1023u) * 4 + (cc >> 3)],
                                  1u << ((cc & 7) * 4));
                    }
                }
            }
        }
        if (t == 0 && (count & 1u)) {
            unsigned int v = ((const unsigned short*)e32)[count - 1];
            unsigned int c0 = v >> 10;
            if ((c0 & 32u) == hsel) {
                unsigned int cc = c0 & 31u;
                atomicAdd(&h[(v & 1023u) * 4 + (cc >> 3)], 1u << ((cc & 7) * 4));
            }
        }
        __syncthreads();
        // merged: this block owns words [cg*8 + half*4 .. +4) of each bin row
        for (int i = t; i < 4096; i += 256) {
            int binlo = i >> 2, wq = i & 3;
            int bin = bc * 1024 + binlo;
            if (bin < 16000)
                merged[(unsigned)bin * 128u + (unsigned)(cg * 8 + half * 4 + wq)]
                    = h[i];
        }
        // ---- encoder: 1024 rows x 32 cells, 4 chunks of 256 rows ----
        int c32 = t & 31, sub = t >> 5;     // 8 subwave groups
        int sh = (c32 & 7) * 4, widx = c32 >> 3;
        float acc[NHID_];
#pragma unroll
        for (int j = 0; j < NHID_; ++j) acc[j] = 0.f;
        for (int q = 0; q < 4; ++q) {
            __syncthreads();               // prev chunk's w1s reads done
            int wbase = (bc * 1024 + q * 256) * NHID_;
#pragma unroll
            for (int r = 0; r < 16; ++r) {
                int i = r * 256 + t;
                int gi = wbase + i;
                w1s[i] = (gi < 16000 * NHID_) ? W1[gi] : 0.f;
            }
            __syncthreads();
            const float4* w1v = (const float4*)w1s;
            int rl0 = q * 256 + sub * 32;
            // rows >= 16000: h==0 => xv=log(1)=0 and w1s staged 0 => no-op,
            // so no guard needed.
#pragma unroll 4
            for (int bl = 0; bl < 32; ++bl) {
                int rl = rl0 + bl;           // hist row 0..1023
                int rwc = sub * 32 + bl;     // w1s row 0..255
                unsigned int w = h[rl * 4 + widx];
                float xv = __logf((float)(((w >> sh) & 0xfu) + 1u));
                float4 wa = w1v[rwc * 4 + 0];
                float4 wb = w1v[rwc * 4 + 1];
                float4 wc = w1v[rwc * 4 + 2];
                float4 wd = w1v[rwc * 4 + 3];
                acc[0] = fmaf(xv, wa.x, acc[0]);  acc[1] = fmaf(xv, wa.y, acc[1]);
                acc[2] = fmaf(xv, wa.z, acc[2]);  acc[3] = fmaf(xv, wa.w, acc[3]);
                acc[4] = fmaf(xv, wb.x, acc[4]);  acc[5] = fmaf(xv, wb.y, acc[5]);
                acc[6] = fmaf(xv, wb.z, acc[6]);  acc[7] = fmaf(xv, wb.w, acc[7]);
                acc[8] = fmaf(xv, wc.x, acc[8]);  acc[9] = fmaf(xv, wc.y, acc[9]);
                acc[10] = fmaf(xv, wc.z, acc[10]); acc[11] = fmaf(xv, wc.w, acc[11]);
                acc[12] = fmaf(xv, wd.x, acc[12]); acc[13] = fmaf(xv, wd.y, acc[13]);
                acc[14] = fmaf(xv, wd.z, acc[14]); acc[15] = fmaf(xv, wd.w, acc[15]);
            }
        }
        __syncthreads();               // w1s dead; reuse as reduction sp
        float* sp = (float*)w1s;       // [8 subs][16 j][32 c] = 4096 floats
#pragma unroll
        for (int j = 0; j < NHID_; ++j) sp[sub * 512 + j * 32 + c32] = acc[j];
        __syncthreads();
        for (int i = t; i < 512; i += 256) {
            int j = i >> 5, cc = i & 31;
            float v = 0.f;
#pragma unroll
            for (int s = 0; s < 8; ++s) v += sp[s * 512 + j * 32 + cc];
            atomicAdd(&hT[j * C_ + cg * 64 + half * 32 + cc], v);
        }
    } else {
        // ---- per-bucket frag counts -> u8 ----
        int bk = bid - 512, cg = bk >> 4, gc = bk & 15;
        for (int i = t; i < 2048; i += 256) h[i] = 0;
        __syncthreads();
        unsigned int count = gcnt_f[bk];
        if (count > RCAP_FRAG) count = RCAP_FRAG;
        const unsigned short* e = entf + (size_t)bk * RCAP_FRAG;
#pragma unroll 4
        for (unsigned int p = t; p < count; p += 256) {
            unsigned int v = e[p];
            unsigned int g_lo = v & 63u;
            unsigned int c_lo = (v >> 6) & 63u;
            atomicAdd(&h[g_lo * 32 + (c_lo >> 1)], 1u << ((c_lo & 1) * 16));
        }
        __syncthreads();
        for (int i = t; i < 1024; i += 256) {
            int g_lo = i >> 4, wb = i & 15;
            unsigned int lo = h[g_lo * 32 + wb * 2];
            unsigned int hi = h[g_lo * 32 + wb * 2 + 1];
            unsigned int outv = (lo & 0xffu) | (((lo >> 16) & 0xffu) << 8)
                              | ((hi & 0xffu) << 16) | (((hi >> 16) & 0xffu) << 24);
            int g = gc * 64 + g_lo;
            if (g < G_)
                fragw[(unsigned)g * 256u + (unsigned)cg * 16u + wb] = outv;
        }
    }
}

// --- 3. latent: BN stats from hT (f64, per block) + sample + KL ------------
__global__ __launch_bounds__(256)
void latent_kernel(const float* __restrict__ hT,     // [16][1024]
                   const float* __restrict__ gamma,
                   const float* __restrict__ beta,
                   const float* __restrict__ W_loc,   // [16][50]
                   const float* __restrict__ b_loc,
                   const float* __restrict__ W_scale, // [16][50]
                   const float* __restrict__ b_scale,
                   const float* __restrict__ eps,     // [1024][50]
                   float* __restrict__ latT,          // [50][1024]
                   __hip_bfloat16* __restrict__ latbf,// [1024][64]
                   double* __restrict__ dacc) {       // [64]
    __shared__ float scs[NHID_], shs[NHID_];
    int t = threadIdx.x;
    {   // phase 1: per-block redundant BN stats (hT is 64 KB, L2-hot)
        int j = t >> 4, cl = t & 15;
        double s1 = 0.0, s2 = 0.0;
#pragma unroll 8
        for (int k = 0; k < 64; ++k) {
            float v = hT[j * C_ + cl + k * 16];
            s1 += (double)v; s2 += (double)v * (double)v;
        }
#pragma unroll
        for (int m = 1; m < 16; m <<= 1) {   // reduce 16-lane groups (same j)
            s1 += __shfl_xor(s1, m);
            s2 += __shfl_xor(s2, m);
        }
        if (cl == 0) {
            double mean = s1 * (1.0 / C_);
            double var = s2 * (1.0 / C_) - mean * mean;
            float rstd = rsqrtf((float)var + 1e-5f);
            float sc = gamma[j] * rstd;
            scs[j] = sc;
            shs[j] = beta[j] - (float)mean * sc;
        }
    }
    __syncthreads();
    int idx = blockIdx.x * 256 + t;
    float kl = 0.f;
    {
        int c = idx / L_;
        int l = idx - c * L_;
        float hb[NHID_];
#pragma unroll
        for (int j = 0; j < NHID_; ++j) {
            float v = fmaf(hT[j * C_ + c], scs[j], shs[j]);
            hb[j] = v > 0.f ? v : 0.f;
        }
        float loc = b_loc[l], ls = b_scale[l];
#pragma unroll
        for (int j = 0; j < NHID_; ++j) {
            loc = fmaf(hb[j], W_loc[j * L_ + l], loc);
            ls  = fmaf(hb[j], W_scale[j * L_ + l], ls);
        }
        float qs = 0.1f * __expf(ls);
        float e = eps[idx];
        float lat = fmaf(qs, e, loc);
        latT[(size_t)l * C_ + c] = lat;
        latbf[c * 64 + l] = __float2bfloat16(lat);
        if (l < 14) latbf[c * 64 + 50 + l] = __float2bfloat16(0.f);  // k-pad
        float z = (lat - loc) / qs;
        kl = fmaf(-0.5f * lat, lat, fmaf(0.5f * z, z, __logf(qs)));
    }
    float s = block_sum_256(kl);
    if (threadIdx.x == 0)
        atomAddF64(&dacc[blockIdx.x & 63], (double)(-CELL_SCALE * s));
}

// --- 4. mixture (swapped-operand MFMA, lane-local softmax) + Poisson -------
// r20: grid (1000, 2): block (g, y) covers 512 cells (8 tiles/wave, 2
// Poisson cells/thread) — halves per-block fixed costs vs (1000,4).
__global__ __launch_bounds__(256)
void mixpois_kernel(const __hip_bfloat16* __restrict__ latbf, // [1024][64]
                    const __hip_bfloat16* __restrict__ lwT,   // [1000][16][64]
                    const unsigned int* __restrict__ merged,  // [16000][128]
                    const float* __restrict__ baseline,       // [1000][16]
                    const float* __restrict__ latT,           // [50][1024]
                    const float* __restrict__ rw,             // [1000][50]
                    const float* __restrict__ rho_bias,
                    const int* __restrict__ libsize,
                    const unsigned char* __restrict__ fragb,  // [1000][1024]
                    double* __restrict__ dacc,                // [64]
                    unsigned int* __restrict__ done,          // zeroed
                    float* __restrict__ out) {
    int g = blockIdx.x;
    int y = blockIdx.y;
    int t = threadIdx.x;
    int lane = t & 63;
    int wv = t >> 6;
    int s16 = lane & 15;           // A row sel (comp) AND B col sel (cell)
    int quad = lane >> 4;
    const __hip_bfloat16* bb = lwT + (size_t)g * 1024 + s16 * 64 + quad * 8;
    short8 lw1 = *(const short8*)bb;
    short8 lw2 = *(const short8*)(bb + 32);
    const float4 bl4 = *(const float4*)(baseline + g * K_ + quad * 4);
    const unsigned int* mrow =
        merged + (size_t)(g * K_ + quad * 4) * 128u;   // +r*128 per reg
    float partial = 0.f;
    int cwave = y * 512 + wv * 128;
#pragma unroll
    for (int mt = 0; mt < 8; ++mt) {
        int c0 = cwave + mt * 16;
        const __hip_bfloat16* aa = latbf + (size_t)(c0 + s16) * 64 + quad * 8;
        short8 la1 = *(const short8*)aa;
        short8 la2 = *(const short8*)(aa + 32);
        f32x4 d = {bl4.x, bl4.y, bl4.z, bl4.w};
        d = __builtin_amdgcn_mfma_f32_16x16x32_bf16(lw1, la1, d, 0, 0, 0);
        d = __builtin_amdgcn_mfma_f32_16x16x32_bf16(lw2, la2, d, 0, 0, 0);
        float m = fmaxf(fmaxf(d[0], d[1]), fmaxf(d[2], d[3]));
        m = fmaxf(m, __shfl_xor(m, 16));
        m = fmaxf(m, __shfl_xor(m, 32));
        float e0 = __expf(d[0] - m), e1 = __expf(d[1] - m);
        float e2 = __expf(d[2] - m), e3 = __expf(d[3] - m);
        float S = (e0 + e1) + (e2 + e3);
        S += __shfl_xor(S, 16);
        S += __shfl_xor(S, 32);
        float lse = m + __logf(S);
        int cp = c0 + s16;
        unsigned int widx = (unsigned)cp >> 3;
        int sb = (cp & 7) * 4;
#pragma unroll
        for (int r = 0; r < 4; ++r) {
            float cnt = (float)((mrow[r * 128u + widx] >> sb) & 0xfu);
            partial = fmaf(cnt, d[r] - lse, partial);
        }
    }
    // ---- Poisson for the same 512-cell tile (2 cells/thread) ----
    float v;
    {
        const float* rwg = rw + (size_t)g * L_;   // hoists to SGPRs
        int cA = y * 512 + t, cB = cA + 256;
        float rhoA = 0.f, rhoB = 0.f;
#pragma unroll 10
        for (int l = 0; l < L_; ++l) {
            float wl = rwg[l];
            rhoA = fmaf(latT[l * C_ + cA], wl, rhoA);
            rhoB = fmaf(latT[l * C_ + cB], wl, rhoB);
        }
        unsigned int fcA = fragb[(size_t)g * C_ + cA];
        unsigned int fcB = fragb[(size_t)g * C_ + cB];
        float rb = rho_bias[g];
        float feA = rb * __expf(rhoA) * (float)libsize[cA];
        float feB = rb * __expf(rhoB) * (float)libsize[cB];
        float lfA = fmaf((float)fcA, __logf(feA), -feA) - LGT[fcA > 31u ? 31u : fcA];
        float lfB = fmaf((float)fcB, __logf(feB), -feB) - LGT[fcB > 31u ? 31u : fcB];
        v = fmaf(-CUT_SCALE, partial, -CELL_SCALE * (lfA + lfB));
    }
    float contrib = block_sum_256(v);
    // ---- fence-free fused final: atomic f64 accumulate + 2-level counter --
    __shared__ int lastflag;
    if (threadIdx.x == 0) {
        lastflag = 0;
        int slot = blockIdx.x & 63;
        double oldv = atomAddF64(&dacc[slot], (double)contrib);
        unsigned inc = 1u;
        float dep = (float)oldv;
        asm volatile("" : "+v"(inc) : "v"(dep));
        unsigned quota = ((slot < 40) ? 16u : 15u) * 2u;   // 1000 = 15*64+40
        if (atomicAdd(&done[slot * 16], inc) == quota - 1u) {
            if (atomicAdd(&done[1024], 1u) == 63u) lastflag = 1;
        }
    }
    __syncthreads();
    if (lastflag) {
        if (t < 64) {
            double dv = atomAddF64(&dacc[t], 0.0);
#pragma unroll
            for (int m = 1; m < 64; m <<= 1) dv += __shfl_xor(dv, m);
            if (t == 0)
                out[0] = (float)(dv - 138629436.11198905); // -12.5*4e6*log16
        }
    }
}

extern "C" void kernel_launch(void* const* d_in, const int* in_sizes, int n_in,
                              void* d_out, int out_size, void* d_ws, size_t ws_size,
                              hipStream_t stream) {
    const float* cut_coord = (const float*)d_in[0];
    const float* eps       = (const float*)d_in[1];
    const float* enc_W1    = (const float*)d_in[2];
    // d_in[3] = enc_b1 : cancels through BatchNorm, unused
    const float* bn_gamma  = (const float*)d_in[4];
    const float* bn_beta   = (const float*)d_in[5];
    const float* W_loc     = (const float*)d_in[6];
    const float* b_loc     = (const float*)d_in[7];
    const float* W_scale   = (const float*)d_in[8];
    const float* b_scale   = (const float*)d_in[9];
    const float* logit_w   = (const float*)d_in[10];
    const float* rho_w     = (const float*)d_in[11];
    const float* baseline  = (const float*)d_in[12];
    const float* rho_bias  = (const float*)d_in[13];
    const int* cut_cxg     = (const int*)d_in[14];
    const int* frag_ix     = (const int*)d_in[16];
    const int* libsize     = (const int*)d_in[19];

    int n_cuts  = in_sizes[0];
    int n_frags = in_sizes[16];

    char* ws = (char*)d_ws;
    unsigned int*   gcnt_c = (unsigned int*)(ws + GCNTC_OFF);
    unsigned int*   gcnt_f = (unsigned int*)(ws + GCNTF_OFF);
    unsigned int*   done   = (unsigned int*)(ws + DONE_OFF);
    double*         dacc   = (double*)(ws + DACC_OFF);
    float*          hT     = (float*)(ws + HT_OFF);
    __hip_bfloat16* latbf  = (__hip_bfloat16*)(ws + LATBF_OFF);
    __hip_bfloat16* lwT    = (__hip_bfloat16*)(ws + LWT_OFF);
    unsigned short* entc   = (unsigned short*)(ws + ENTC_OFF);
    unsigned short* entf   = (unsigned short*)(ws + ENTF_OFF);
    unsigned int*   merged = (unsigned int*)(ws + MERGED_OFF);
    unsigned int*   fragw  = (unsigned int*)(ws + FRAGU8_OFF);
    float*          latT   = (float*)(ws + LATT_OFF);
    float*          out    = (float*)d_out;

    int ncc = (n_cuts + CHUNK_ - 1) / CHUNK_;
    int ncf = (n_frags + CHUNK_ - 1) / CHUNK_;
    int nblk_part = ncc + ncf;

    hipMemsetAsync(ws, 0, ZERO_BYTES, stream);   // gcnt + done + dacc + hT

    part_kernel<<<nblk_part + 512, 256, 0, stream>>>(
        cut_cxg, cut_coord, frag_ix, gcnt_c, gcnt_f, entc, entf,
        logit_w, rho_w, lwT, dacc,
        n_cuts, n_frags, ncc, nblk_part);
    mid_kernel<<<768, 256, 0, stream>>>(
        gcnt_c, entc, gcnt_f, entf, enc_W1, merged, fragw, hT);
    latent_kernel<<<(C_ * L_) / 256, 256, 0, stream>>>(
        hT, bn_gamma, bn_beta, W_loc, b_loc, W_scale, b_scale,
        eps, latT, latbf, dacc);
    mixpois_kernel<<<dim3(G_, 2), 256, 0, stream>>>(
        latbf, lwT, merged, baseline, latT, rho_w, rho_bias, libsize,
        (const unsigned char*)fragw, dacc, done, out);
}

// Round 8
// 219.480 us; speedup vs baseline: 1.1397x; 1.0053x over previous
//
#include <hip/hip_runtime.h>
#include <hip/hip_bf16.h>
#include <math.h>

// ---------------------------------------------------------------------------
// VAE ELBO (chromatin VAE). Sizes fixed by the reference.
//
//  * NB_ENC == NB_DEC == 16, identical binning => ONE nibble histogram serves
//    both the encoder input (log1p counts) and the mixture likelihood.
//  * r3-r5: global per-record atomics too slow => two-phase LDS counting sort.
//  * r7: same-address atomics serialize ~16ns => per-block partial stores.
//  * r8: roles fused as block-ranges.
//  * r12: hipLaunchCooperativeKernel DOES NOT RUN under this harness.
//  * r13: part = register-staged single pass; mid = hist+enc / frag only.
//  * r14: __threadfence = L2 wb/inv on 8 non-coherent XCD L2s => +138us. BAN.
//  * r15: fence-free tail: f64 atomics into dacc[64]; returning-atomic
//    data-dep orders done-counter.
//  * r16: swapped-operand MFMA => lane-local softmax; Poisson fused in.
//  * r17: 1024-bucket partition REGRESSED part (write amp). REVERTED.
//  * r18: 48KB-LDS mid REGRESSED (2 blocks/CU, latency-bound). REVERTED.
//  * r19: mid split by CELLS (2 blocks/bucket, 32KB LDS, grid 768): WIN.
//  * r20: part rank-from-count (scatter atomics removed); mixpois (1000,2).
//  * r21 (this round): mid WRITE_SIZE 18MB vs ~9MB logical — merged writes
//    were 16B runs @512B stride => 64B-sector RMW amplification. FIX:
//    merged relaid as [cg*2+half][bin][4w] so each block writes ONE
//    contiguous 16KB run (mixpois recomputes base accordingly). Encoder's
//    128x __logf/thread (quarter-rate pipe) => 16-entry LDS LUT (counts are
//    4-bit), shifting work to the idle LDS pipe.
// ---------------------------------------------------------------------------

#define G_      1000
#define C_      1024
#define L_      50
#define K_      16
#define NHID_   16
#define CUT_SCALE   12.5f          // N_TOTAL_CUTS / N_CUTS
#define CELL_SCALE  9.765625f      // N_TOTAL_CELLS / N_CELLS

#define CHUNK_    6144
#define RCAP_CUT  18432            // bucket capacity, cuts  (mean 16000)
#define RCAP_FRAG 9216             // bucket capacity, frags (mean 8000)

// ws layout (bytes); [0, ZERO_BYTES) memset per call (gcnt + done + dacc + hT).
#define GCNTC_OFF  0ull
#define GCNTF_OFF  1024ull
#define DONE_OFF   2048ull         // u32: 64 slots @ stride 16 u32, lvl2 @ [1024]
#define DACC_OFF   6400ull         // f64[64] global ELBO accumulator slots
#define HT_OFF     6912ull         // f32 [16][1024] (atomic-accumulated by mid)
#define ZERO_BYTES 72448ull
#define LATBF_OFF  72448ull        // bf16 [1024][64]
#define LWT_OFF    203520ull       // bf16 [1000][16][64]
#define ENTC_OFF   2251520ull      // u16 [256][18432]
#define ENTF_OFF   11688704ull     // u16 [256][9216]
#define MERGED_OFF 16407296ull     // u32 [32 cg*2+half][16000 bin][4 w]
#define FRAGU8_OFF 24599296ull     // u8  [1000][1024]
#define LATT_OFF   25623296ull     // f32 [50][1024]
#define WS_NEED    25828096ull

typedef __attribute__((ext_vector_type(8))) short short8;
typedef __attribute__((ext_vector_type(4))) float f32x4;

__device__ __constant__ float LGT[32] = {   // log(n!)
    0.0f, 0.0f, 0.6931471805599453f, 1.791759469228055f, 3.1780538303479458f,
    4.787491742782046f, 6.579251212010101f, 8.525161361065415f,
    10.60460290274525f, 12.801827480081469f, 15.104412573075516f,
    17.502307845873887f, 19.987214495661885f, 22.552163853123425f,
    25.19122118273868f, 27.89927138384089f, 30.671860106080672f,
    33.50507345013689f, 36.39544520803305f, 39.339884187199495f,
    42.335616460753485f, 45.38013889847691f, 48.47118135183523f,
    51.60667556776438f, 54.78472939811232f, 58.00360522298052f,
    61.261701761002f, 64.55753862700633f, 67.88974313718154f,
    71.25703896716801f, 74.65823634883016f, 78.0922235533153f };

// f64 atomic add at the device coherent point (returns old value; the return
// is used to fabricate ordering dependencies — NO fences anywhere).
__device__ __forceinline__ double atomAddF64(double* p, double v) {
    return __hip_atomic_fetch_add(p, v, __ATOMIC_RELAXED,
                                  __HIP_MEMORY_SCOPE_AGENT);
}

__device__ __forceinline__ float block_sum_256(float v) {
    __shared__ float sm[256];
    int t = threadIdx.x;
    __syncthreads();
    sm[t] = v;
    __syncthreads();
#pragma unroll
    for (int s = 128; s > 0; s >>= 1) {
        if (t < s) sm[t] += sm[t + s];
        __syncthreads();
    }
    return sm[0];
}

// --- 1. part: [0,nblk_part) radix partition (rank-from-count, no scatter
//        atomics) | [nblk_part, +256) lwprep | [+256, +512) wkl -------------
__global__ __launch_bounds__(256)
void part_kernel(const int* __restrict__ cut_ix,
                 const float* __restrict__ coord,
                 const int* __restrict__ frag_ix,
                 unsigned int* __restrict__ gcnt_c,
                 unsigned int* __restrict__ gcnt_f,
                 unsigned short* __restrict__ entc,
                 unsigned short* __restrict__ entf,
                 const float* __restrict__ lw,      // [1000][50][16]
                 const float* __restrict__ rw,      // [1000][50]
                 __hip_bfloat16* __restrict__ lwT,  // [1000][16][64]
                 double* __restrict__ dacc,         // [64]
                 int n_cuts, int n_frags, int ncc, int nblk_part) {
    int t = threadIdx.x;
    int bid = blockIdx.x;
    if (bid >= nblk_part) {
        int r = bid - nblk_part;
        if (r < 256) {
            // ---- lwprep: bf16 transpose [g][n][64], k-pads zeroed ----
            for (int g = r; g < G_; g += 256) {
                for (int i = t; i < L_ * K_; i += 256) {
                    float v = lw[(size_t)g * (L_ * K_) + i];
                    lwT[(size_t)g * 1024 + (i & 15) * 64 + (i >> 4)] =
                        __float2bfloat16(v);
                }
                for (int i = t; i < 16 * 14; i += 256) {
                    int n = i / 14, l = 50 + (i % 14);
                    lwT[(size_t)g * 1024 + n * 64 + l] = __float2bfloat16(0.f);
                }
            }
        } else {
            // ---- weight KL ----
            const int NTOT = G_ * L_ * K_ + G_ * L_;   // 850000
            int wb = r - 256;
            float s = 0.f;
            for (int i = wb * 256 + t; i < NTOT; i += 256 * 256) {
                float w = (i < G_ * L_ * K_) ? lw[i] : rw[i - G_ * L_ * K_];
                s += fmaf(-50.f * w, w, 1.3836465597893733f);
            }
            s = block_sum_256(s);
            if (t == 0) atomAddF64(&dacc[wb & 63], (double)(-s));
        }
        return;
    }
    // ---- radix partition, one 6144-record chunk per block ----
    __shared__ unsigned int cnt[256], excl[256], gbas[256];
    __shared__ unsigned short stage[CHUNK_];
    __shared__ unsigned char bkof[CHUNK_];
    bool isCut = (bid < ncc);
    int blk = isCut ? bid : bid - ncc;
    const int* idx = isCut ? cut_ix : frag_ix;
    int n = isCut ? n_cuts : n_frags;
    int rcap = isCut ? RCAP_CUT : RCAP_FRAG;
    unsigned int* gcount = isCut ? gcnt_c : gcnt_f;
    unsigned short* ent = isCut ? entc : entf;
    int i0 = blk * CHUNK_;
    cnt[t] = 0;
    // stage 24 records in registers: 6 int4 (+6 float4 for cuts), all in flight
    int4 I[6]; float4 X[6];
    unsigned int vm;
    bool full = (i0 + CHUNK_ <= n);
    if (full) {
        const int4* ip = (const int4*)(idx + i0);
#pragma unroll
        for (int k = 0; k < 6; ++k) I[k] = ip[k * 256 + t];
        if (isCut) {
            const float4* xp = (const float4*)(coord + i0);
#pragma unroll
            for (int k = 0; k < 6; ++k) X[k] = xp[k * 256 + t];
        }
        vm = 0xFFFFFFu;
    } else {
        vm = 0;
#pragma unroll
        for (int k = 0; k < 6; ++k) {
            int r0 = i0 + (k * 256 + t) * 4;
            int* Ii = (int*)&I[k]; float* Xi = (float*)&X[k];
#pragma unroll
            for (int u = 0; u < 4; ++u) {
                bool v = (r0 + u) < n;
                if (v) vm |= 1u << (k * 4 + u);
                Ii[u] = v ? idx[r0 + u] : 0;
                Xi[u] = (v && isCut) ? coord[r0 + u] : 0.f;
            }
        }
    }
    __syncthreads();
    // count phase: compute (e,bk) ONCE, rank = returning atomic; cache all
    // three in the now-dead I/X registers (r20).
#pragma unroll
    for (int k = 0; k < 6; ++k) {
        int* Ii = (int*)&I[k];
        unsigned int* Xi = (unsigned int*)&X[k];
#pragma unroll
        for (int u = 0; u < 4; ++u) {
            if (vm & (1u << (k * 4 + u))) {
                int ix = Ii[u];
                int c = ix / G_;
                int g = ix - c * G_;
                unsigned int bk; unsigned int e;
                if (isCut) {
                    float xf = ((const float*)Xi)[u];
                    int b = (int)(xf * 16.f); b = b > 15 ? 15 : b;
                    int bin = g * K_ + b;
                    bk = ((unsigned)(c >> 6) << 4) | ((unsigned)bin >> 10);
                    e = ((unsigned)(c & 63) << 10) | ((unsigned)bin & 1023u);
                } else {
                    bk = ((unsigned)(c >> 6) << 4) | ((unsigned)g >> 6);
                    e = ((unsigned)(c & 63) << 6) | ((unsigned)g & 63u);
                }
                unsigned int rank = atomicAdd(&cnt[bk], 1u);  // LDS, returning
                Ii[u] = (int)(e | (bk << 16));
                Xi[u] = rank;
            }
        }
    }
    __syncthreads();
    // exclusive prefix over 256 bucket counts, single wave, shfl scan
    if (t < 64) {
        unsigned int c0 = cnt[t * 4 + 0], c1 = cnt[t * 4 + 1];
        unsigned int c2 = cnt[t * 4 + 2], c3 = cnt[t * 4 + 3];
        unsigned int tot = c0 + c1 + c2 + c3;
        unsigned int run = tot;
#pragma unroll
        for (int o = 1; o < 64; o <<= 1) {
            unsigned int v = __shfl_up(run, o, 64);
            if (t >= o) run += v;
        }
        unsigned int base = run - tot;          // exclusive over 4-groups
        excl[t * 4 + 0] = base;
        excl[t * 4 + 1] = base + c0;
        excl[t * 4 + 2] = base + c0 + c1;
        excl[t * 4 + 3] = base + c0 + c1 + c2;
    }
    __syncthreads();
    gbas[t] = cnt[t] ? atomicAdd(&gcount[t], cnt[t]) : 0u;  // global reserve
    // scatter from registers: p = excl[bk] + rank — NO atomics (r20)
#pragma unroll
    for (int k = 0; k < 6; ++k) {
        const unsigned int* Ii = (const unsigned int*)&I[k];
        const unsigned int* Xi = (const unsigned int*)&X[k];
#pragma unroll
        for (int u = 0; u < 4; ++u) {
            if (vm & (1u << (k * 4 + u))) {
                unsigned int w = Ii[u];
                unsigned int bk = w >> 16;
                unsigned int p = excl[bk] + Xi[u];
                stage[p] = (unsigned short)(w & 0xffffu);
                bkof[p] = (unsigned char)bk;
            }
        }
    }
    __syncthreads();
    int total = n - i0; if (total > CHUNK_) total = CHUNK_;
    for (int p = t; p < total; p += 256) {
        unsigned int bk = bkof[p];
        unsigned int dst = gbas[bk] + (p - excl[bk]);
        if (dst < (unsigned)rcap)
            ent[(size_t)bk * rcap + dst] = stage[p];
    }
}

// --- 2. mid kernel: [0,512) half-cell bucket hist+enc | [512,768) frag -----
// r19: 2 blocks/bucket by CELLS. r21: merged write is one contiguous 16KB
// run per block (no sector RMW); log1p via 16-entry LDS LUT.
__global__ __launch_bounds__(256)
void mid_kernel(const unsigned int* __restrict__ gcnt_c,
                const unsigned short* __restrict__ entc,
                const unsigned int* __restrict__ gcnt_f,
                const unsigned short* __restrict__ entf,
                const float* __restrict__ W1,        // [16000][16]
                unsigned int* __restrict__ merged,   // [32][16000][4]
                unsigned int* __restrict__ fragw,    // u8[1000][1024] as u32
                float* __restrict__ hT) {            // [16][1024], pre-zeroed
    __shared__ unsigned int h[4096];   // 16 KB: [1024 bins][4w of 8 cells]
    __shared__ float w1s[4096];        // 16 KB W1 chunk stage / reduction sp
    __shared__ float lgl[16];          // log1p LUT (counts are 4-bit)
    int t = threadIdx.x;
    int bid = blockIdx.x;
    if (bid < 512) {
        // ---- half-cell bucket: 1024 bins x 32 cells ----
        int bk = bid >> 1, half = bid & 1;
        int cg = bk >> 4, bc = bk & 15;
        for (int i = t; i < 4096; i += 256) h[i] = 0;
        if (t < 16) lgl[t] = __logf((float)(t + 1));
        __syncthreads();
        unsigned int count = gcnt_c[bk];
        if (count > RCAP_CUT) count = RCAP_CUT;
        const unsigned int* e32 = (const unsigned int*)(entc + (size_t)bk * RCAP_CUT);
        unsigned int hsel = (unsigned)half << 5;
        unsigned int npair = count >> 1;
        for (unsigned int base = 0; base < npair; base += 1024) {
            unsigned int w[4]; bool val[4];
#pragma unroll
            for (int u = 0; u < 4; ++u) {
                unsigned int p = base + u * 256 + t;
                val[u] = (p < npair);
                w[u] = val[u] ? e32[p] : 0u;
            }
#pragma unroll
            for (int u = 0; u < 4; ++u) {
                if (val[u]) {
                    unsigned int v0 = w[u] & 0xffffu, v1 = w[u] >> 16;
                    unsigned int c0 = v0 >> 10, c1 = v1 >> 10;
                    if ((c0 & 32u) == hsel) {
                        unsigned int cc = c0 & 31u;
                        atomicAdd(&h[(v0 & 1023u) * 4 + (cc >> 3)],
                                  1u << ((cc & 7) * 4));
                    }
                    if ((c1 & 32u) == hsel) {
                        unsigned int cc = c1 & 31u;
                        atomicAdd(&h[(v1 & 1023u) * 4 + (cc >> 3)],
                                  1u << ((cc & 7) * 4));
                    }
                }
            }
        }
        if (t == 0 && (count & 1u)) {
            unsigned int v = ((const unsigned short*)e32)[count - 1];
            unsigned int c0 = v >> 10;
            if ((c0 & 32u) == hsel) {
                unsigned int cc = c0 & 31u;
                atomicAdd(&h[(v & 1023u) * 4 + (cc >> 3)], 1u << ((cc & 7) * 4));
            }
        }
        __syncthreads();
        // merged: ONE contiguous 16KB run per block (r21). bins>=16000 don't
        // exist (g*16+b <= 15999), so bc==15 writes only the first 640 rows.
        {
            unsigned int mbase = ((unsigned)(cg * 2 + half)) * 64000u
                               + (unsigned)bc * 4096u;
            int lim = (bc == 15) ? 2560 : 4096;
            for (int i = t; i < lim; i += 256)
                merged[mbase + i] = h[i];
        }
        // ---- encoder: 1024 rows x 32 cells, 4 chunks of 256 rows ----
        int c32 = t & 31, sub = t >> 5;     // 8 subwave groups
        int sh = (c32 & 7) * 4, widx = c32 >> 3;
        float acc[NHID_];
#pragma unroll
        for (int j = 0; j < NHID_; ++j) acc[j] = 0.f;
        for (int q = 0; q < 4; ++q) {
            __syncthreads();               // prev chunk's w1s reads done
            int wbase = (bc * 1024 + q * 256) * NHID_;
#pragma unroll
            for (int r = 0; r < 16; ++r) {
                int i = r * 256 + t;
                int gi = wbase + i;
                w1s[i] = (gi < 16000 * NHID_) ? W1[gi] : 0.f;
            }
            __syncthreads();
            const float4* w1v = (const float4*)w1s;
            int rl0 = q * 256 + sub * 32;
            // rows >= 16000: h==0 => xv=log(1)=0 and w1s staged 0 => no-op.
#pragma unroll 4
            for (int bl = 0; bl < 32; ++bl) {
                int rl = rl0 + bl;           // hist row 0..1023
                int rwc = sub * 32 + bl;     // w1s row 0..255
                unsigned int w = h[rl * 4 + widx];
                float xv = lgl[(w >> sh) & 0xfu];   // r21: LUT, not __logf
                float4 wa = w1v[rwc * 4 + 0];
                float4 wb = w1v[rwc * 4 + 1];
                float4 wc = w1v[rwc * 4 + 2];
                float4 wd = w1v[rwc * 4 + 3];
                acc[0] = fmaf(xv, wa.x, acc[0]);  acc[1] = fmaf(xv, wa.y, acc[1]);
                acc[2] = fmaf(xv, wa.z, acc[2]);  acc[3] = fmaf(xv, wa.w, acc[3]);
                acc[4] = fmaf(xv, wb.x, acc[4]);  acc[5] = fmaf(xv, wb.y, acc[5]);
                acc[6] = fmaf(xv, wb.z, acc[6]);  acc[7] = fmaf(xv, wb.w, acc[7]);
                acc[8] = fmaf(xv, wc.x, acc[8]);  acc[9] = fmaf(xv, wc.y, acc[9]);
                acc[10] = fmaf(xv, wc.z, acc[10]); acc[11] = fmaf(xv, wc.w, acc[11]);
                acc[12] = fmaf(xv, wd.x, acc[12]); acc[13] = fmaf(xv, wd.y, acc[13]);
                acc[14] = fmaf(xv, wd.z, acc[14]); acc[15] = fmaf(xv, wd.w, acc[15]);
            }
        }
        __syncthreads();               // w1s dead; reuse as reduction sp
        float* sp = (float*)w1s;       // [8 subs][16 j][32 c] = 4096 floats
#pragma unroll
        for (int j = 0; j < NHID_; ++j) sp[sub * 512 + j * 32 + c32] = acc[j];
        __syncthreads();
        for (int i = t; i < 512; i += 256) {
            int j = i >> 5, cc = i & 31;
            float v = 0.f;
#pragma unroll
            for (int s = 0; s < 8; ++s) v += sp[s * 512 + j * 32 + cc];
            atomicAdd(&hT[j * C_ + cg * 64 + half * 32 + cc], v);
        }
    } else {
        // ---- per-bucket frag counts -> u8 ----
        int bk = bid - 512, cg = bk >> 4, gc = bk & 15;
        for (int i = t; i < 2048; i += 256) h[i] = 0;
        __syncthreads();
        unsigned int count = gcnt_f[bk];
        if (count > RCAP_FRAG) count = RCAP_FRAG;
        const unsigned short* e = entf + (size_t)bk * RCAP_FRAG;
#pragma unroll 4
        for (unsigned int p = t; p < count; p += 256) {
            unsigned int v = e[p];
            unsigned int g_lo = v & 63u;
            unsigned int c_lo = (v >> 6) & 63u;
            atomicAdd(&h[g_lo * 32 + (c_lo >> 1)], 1u << ((c_lo & 1) * 16));
        }
        __syncthreads();
        for (int i = t; i < 1024; i += 256) {
            int g_lo = i >> 4, wb = i & 15;
            unsigned int lo = h[g_lo * 32 + wb * 2];
            unsigned int hi = h[g_lo * 32 + wb * 2 + 1];
            unsigned int outv = (lo & 0xffu) | (((lo >> 16) & 0xffu) << 8)
                              | ((hi & 0xffu) << 16) | (((hi >> 16) & 0xffu) << 24);
            int g = gc * 64 + g_lo;
            if (g < G_)
                fragw[(unsigned)g * 256u + (unsigned)cg * 16u + wb] = outv;
        }
    }
}

// --- 3. latent: BN stats from hT (f64, per block) + sample + KL ------------
__global__ __launch_bounds__(256)
void latent_kernel(const float* __restrict__ hT,     // [16][1024]
                   const float* __restrict__ gamma,
                   const float* __restrict__ beta,
                   const float* __restrict__ W_loc,   // [16][50]
                   const float* __restrict__ b_loc,
                   const float* __restrict__ W_scale, // [16][50]
                   const float* __restrict__ b_scale,
                   const float* __restrict__ eps,     // [1024][50]
                   float* __restrict__ latT,          // [50][1024]
                   __hip_bfloat16* __restrict__ latbf,// [1024][64]
                   double* __restrict__ dacc) {       // [64]
    __shared__ float scs[NHID_], shs[NHID_];
    int t = threadIdx.x;
    {   // phase 1: per-block redundant BN stats (hT is 64 KB, L2-hot)
        int j = t >> 4, cl = t & 15;
        double s1 = 0.0, s2 = 0.0;
#pragma unroll 8
        for (int k = 0; k < 64; ++k) {
            float v = hT[j * C_ + cl + k * 16];
            s1 += (double)v; s2 += (double)v * (double)v;
        }
#pragma unroll
        for (int m = 1; m < 16; m <<= 1) {   // reduce 16-lane groups (same j)
            s1 += __shfl_xor(s1, m);
            s2 += __shfl_xor(s2, m);
        }
        if (cl == 0) {
            double mean = s1 * (1.0 / C_);
            double var = s2 * (1.0 / C_) - mean * mean;
            float rstd = rsqrtf((float)var + 1e-5f);
            float sc = gamma[j] * rstd;
            scs[j] = sc;
            shs[j] = beta[j] - (float)mean * sc;
        }
    }
    __syncthreads();
    int idx = blockIdx.x * 256 + t;
    float kl = 0.f;
    {
        int c = idx / L_;
        int l = idx - c * L_;
        float hb[NHID_];
#pragma unroll
        for (int j = 0; j < NHID_; ++j) {
            float v = fmaf(hT[j * C_ + c], scs[j], shs[j]);
            hb[j] = v > 0.f ? v : 0.f;
        }
        float loc = b_loc[l], ls = b_scale[l];
#pragma unroll
        for (int j = 0; j < NHID_; ++j) {
            loc = fmaf(hb[j], W_loc[j * L_ + l], loc);
            ls  = fmaf(hb[j], W_scale[j * L_ + l], ls);
        }
        float qs = 0.1f * __expf(ls);
        float e = eps[idx];
        float lat = fmaf(qs, e, loc);
        latT[(size_t)l * C_ + c] = lat;
        latbf[c * 64 + l] = __float2bfloat16(lat);
        if (l < 14) latbf[c * 64 + 50 + l] = __float2bfloat16(0.f);  // k-pad
        float z = (lat - loc) / qs;
        kl = fmaf(-0.5f * lat, lat, fmaf(0.5f * z, z, __logf(qs)));
    }
    float s = block_sum_256(kl);
    if (threadIdx.x == 0)
        atomAddF64(&dacc[blockIdx.x & 63], (double)(-CELL_SCALE * s));
}

// --- 4. mixture (swapped-operand MFMA, lane-local softmax) + Poisson -------
// r20: grid (1000, 2), 512 cells/block. r21: merged read uses the new
// [cg*2+half][bin][4w] layout.
__global__ __launch_bounds__(256)
void mixpois_kernel(const __hip_bfloat16* __restrict__ latbf, // [1024][64]
                    const __hip_bfloat16* __restrict__ lwT,   // [1000][16][64]
                    const unsigned int* __restrict__ merged,  // [32][16000][4]
                    const float* __restrict__ baseline,       // [1000][16]
                    const float* __restrict__ latT,           // [50][1024]
                    const float* __restrict__ rw,             // [1000][50]
                    const float* __restrict__ rho_bias,
                    const int* __restrict__ libsize,
                    const unsigned char* __restrict__ fragb,  // [1000][1024]
                    double* __restrict__ dacc,                // [64]
                    unsigned int* __restrict__ done,          // zeroed
                    float* __restrict__ out) {
    int g = blockIdx.x;
    int y = blockIdx.y;
    int t = threadIdx.x;
    int lane = t & 63;
    int wv = t >> 6;
    int s16 = lane & 15;           // A row sel (comp) AND B col sel (cell)
    int quad = lane >> 4;
    const __hip_bfloat16* bb = lwT + (size_t)g * 1024 + s16 * 64 + quad * 8;
    short8 lw1 = *(const short8*)bb;
    short8 lw2 = *(const short8*)(bb + 32);
    const float4 bl4 = *(const float4*)(baseline + g * K_ + quad * 4);
    const unsigned int gb = ((unsigned)(g * K_ + quad * 4)) * 4u;  // bin base
    float partial = 0.f;
    int cwave = y * 512 + wv * 128;
#pragma unroll
    for (int mt = 0; mt < 8; ++mt) {
        int c0 = cwave + mt * 16;
        const __hip_bfloat16* aa = latbf + (size_t)(c0 + s16) * 64 + quad * 8;
        short8 la1 = *(const short8*)aa;
        short8 la2 = *(const short8*)(aa + 32);
        f32x4 d = {bl4.x, bl4.y, bl4.z, bl4.w};
        d = __builtin_amdgcn_mfma_f32_16x16x32_bf16(lw1, la1, d, 0, 0, 0);
        d = __builtin_amdgcn_mfma_f32_16x16x32_bf16(lw2, la2, d, 0, 0, 0);
        float m = fmaxf(fmaxf(d[0], d[1]), fmaxf(d[2], d[3]));
        m = fmaxf(m, __shfl_xor(m, 16));
        m = fmaxf(m, __shfl_xor(m, 32));
        float e0 = __expf(d[0] - m), e1 = __expf(d[1] - m);
        float e2 = __expf(d[2] - m), e3 = __expf(d[3] - m);
        float S = (e0 + e1) + (e2 + e3);
        S += __shfl_xor(S, 16);
        S += __shfl_xor(S, 32);
        float lse = m + __logf(S);
        int cp = c0 + s16;
        unsigned int base2 = ((unsigned)cp >> 5) * 64000u
                           + (((unsigned)cp & 31u) >> 3);
        int sb = (cp & 7) * 4;
#pragma unroll
        for (int r = 0; r < 4; ++r) {
            float cnt = (float)((merged[base2 + gb + r * 4u] >> sb) & 0xfu);
            partial = fmaf(cnt, d[r] - lse, partial);
        }
    }
    // ---- Poisson for the same 512-cell tile (2 cells/thread) ----
    float v;
    {
        const float* rwg = rw + (size_t)g * L_;   // hoists to SGPRs
        int cA = y * 512 + t, cB = cA + 256;
        float rhoA = 0.f, rhoB = 0.f;
#pragma unroll 10
        for (int l = 0; l < L_; ++l) {
            float wl = rwg[l];
            rhoA = fmaf(latT[l * C_ + cA], wl, rhoA);
            rhoB = fmaf(latT[l * C_ + cB], wl, rhoB);
        }
        unsigned int fcA = fragb[(size_t)g * C_ + cA];
        unsigned int fcB = fragb[(size_t)g * C_ + cB];
        float rb = rho_bias[g];
        float feA = rb * __expf(rhoA) * (float)libsize[cA];
        float feB = rb * __expf(rhoB) * (float)libsize[cB];
        float lfA = fmaf((float)fcA, __logf(feA), -feA) - LGT[fcA > 31u ? 31u : fcA];
        float lfB = fmaf((float)fcB, __logf(feB), -feB) - LGT[fcB > 31u ? 31u : fcB];
        v = fmaf(-CUT_SCALE, partial, -CELL_SCALE * (lfA + lfB));
    }
    float contrib = block_sum_256(v);
    // ---- fence-free fused final: atomic f64 accumulate + 2-level counter --
    __shared__ int lastflag;
    if (threadIdx.x == 0) {
        lastflag = 0;
        int slot = blockIdx.x & 63;
        double oldv = atomAddF64(&dacc[slot], (double)contrib);
        unsigned inc = 1u;
        float dep = (float)oldv;
        asm volatile("" : "+v"(inc) : "v"(dep));
        unsigned quota = ((slot < 40) ? 16u : 15u) * 2u;   // 1000 = 15*64+40
        if (atomicAdd(&done[slot * 16], inc) == quota - 1u) {
            if (atomicAdd(&done[1024], 1u) == 63u) lastflag = 1;
        }
    }
    __syncthreads();
    if (lastflag) {
        if (t < 64) {
            double dv = atomAddF64(&dacc[t], 0.0);
#pragma unroll
            for (int m = 1; m < 64; m <<= 1) dv += __shfl_xor(dv, m);
            if (t == 0)
                out[0] = (float)(dv - 138629436.11198905); // -12.5*4e6*log16
        }
    }
}

extern "C" void kernel_launch(void* const* d_in, const int* in_sizes, int n_in,
                              void* d_out, int out_size, void* d_ws, size_t ws_size,
                              hipStream_t stream) {
    const float* cut_coord = (const float*)d_in[0];
    const float* eps       = (const float*)d_in[1];
    const float* enc_W1    = (const float*)d_in[2];
    // d_in[3] = enc_b1 : cancels through BatchNorm, unused
    const float* bn_gamma  = (const float*)d_in[4];
    const float* bn_beta   = (const float*)d_in[5];
    const float* W_loc     = (const float*)d_in[6];
    const float* b_loc     = (const float*)d_in[7];
    const float* W_scale   = (const float*)d_in[8];
    const float* b_scale   = (const float*)d_in[9];
    const float* logit_w   = (const float*)d_in[10];
    const float* rho_w     = (const float*)d_in[11];
    const float* baseline  = (const float*)d_in[12];
    const float* rho_bias  = (const float*)d_in[13];
    const int* cut_cxg     = (const int*)d_in[14];
    const int* frag_ix     = (const int*)d_in[16];
    const int* libsize     = (const int*)d_in[19];

    int n_cuts  = in_sizes[0];
    int n_frags = in_sizes[16];

    char* ws = (char*)d_ws;
    unsigned int*   gcnt_c = (unsigned int*)(ws + GCNTC_OFF);
    unsigned int*   gcnt_f = (unsigned int*)(ws + GCNTF_OFF);
    unsigned int*   done   = (unsigned int*)(ws + DONE_OFF);
    double*         dacc   = (double*)(ws + DACC_OFF);
    float*          hT     = (float*)(ws + HT_OFF);
    __hip_bfloat16* latbf  = (__hip_bfloat16*)(ws + LATBF_OFF);
    __hip_bfloat16* lwT    = (__hip_bfloat16*)(ws + LWT_OFF);
    unsigned short* entc   = (unsigned short*)(ws + ENTC_OFF);
    unsigned short* entf   = (unsigned short*)(ws + ENTF_OFF);
    unsigned int*   merged = (unsigned int*)(ws + MERGED_OFF);
    unsigned int*   fragw  = (unsigned int*)(ws + FRAGU8_OFF);
    float*          latT   = (float*)(ws + LATT_OFF);
    float*          out    = (float*)d_out;

    int ncc = (n_cuts + CHUNK_ - 1) / CHUNK_;
    int ncf = (n_frags + CHUNK_ - 1) / CHUNK_;
    int nblk_part = ncc + ncf;

    hipMemsetAsync(ws, 0, ZERO_BYTES, stream);   // gcnt + done + dacc + hT

    part_kernel<<<nblk_part + 512, 256, 0, stream>>>(
        cut_cxg, cut_coord, frag_ix, gcnt_c, gcnt_f, entc, entf,
        logit_w, rho_w, lwT, dacc,
        n_cuts, n_frags, ncc, nblk_part);
    mid_kernel<<<768, 256, 0, stream>>>(
        gcnt_c, entc, gcnt_f, entf, enc_W1, merged, fragw, hT);
    latent_kernel<<<(C_ * L_) / 256, 256, 0, stream>>>(
        hT, bn_gamma, bn_beta, W_loc, b_loc, W_scale, b_scale,
        eps, latT, latbf, dacc);
    mixpois_kernel<<<dim3(G_, 2), 256, 0, stream>>>(
        latbf, lwT, merged, baseline, latT, rho_w, rho_bias, libsize,
        (const unsigned char*)fragw, dacc, done, out);
}